// Round 16
// baseline (4474.959 us; speedup 1.0000x reference)
//
#include <hip/hip_runtime.h>
#include <hip/hip_bf16.h>

#define CB 256      // batch
#define CN 256      // nodes
#define CK 3        // children per node
#define CE 256      // embedding dim
#define CH 256      // hidden dim
#define CG_ 1536    // gates = 6*CH
#define KTOT 1024   // E + K*H
#define ROWS 32     // rows per chunk (r16: 2x B-panel reuse)
#define ASTRW 1028  // Apk row stride in u32 words (pad +4: 2-way-conflict-free)

typedef __attribute__((ext_vector_type(8))) short short8v;          // 8 bf16
typedef __attribute__((ext_vector_type(4))) float float4v;          // MFMA C/D
typedef __attribute__((ext_vector_type(4))) unsigned int uint4v;
typedef __attribute__((ext_vector_type(4))) unsigned short ushort4v;
typedef unsigned int u32;
typedef unsigned long long u64;
typedef unsigned short u16;

__device__ __forceinline__ u16 f2bfu(float v) {
    __hip_bfloat16 h = __float2bfloat16(v);
    return __builtin_bit_cast(u16, h);
}
__device__ __forceinline__ float bfu2f(u16 u) {
    __hip_bfloat16 h = __builtin_bit_cast(__hip_bfloat16, u);
    return __bfloat162float(h);
}

// ---------------------------------------------------------------------------
// Prep (verified r8-r15): split virtual W = [Wx_w ; Uh_w] (1024 x 1536) into
// K-major bf16 hi/lo planes [g][k].
// ---------------------------------------------------------------------------
__global__ __launch_bounds__(256) void prep_w(
    const float* __restrict__ Wx_w, const float* __restrict__ Uh_w,
    u16* __restrict__ Whi, u16* __restrict__ Wlo)
{
    const int g = blockIdx.x;
    for (int k = threadIdx.x; k < KTOT; k += 256) {
        float w = (k < CE) ? Wx_w[(size_t)k * CG_ + g]
                           : Uh_w[(size_t)(k - CE) * CG_ + g];
        u16 hi = f2bfu(w);
        Whi[(size_t)g * KTOT + k] = hi;
        Wlo[(size_t)g * KTOT + k] = f2bfu(w - bfu2f(hi));
    }
}

// ---------------------------------------------------------------------------
// Level schedule build (verified r14/r15, incl. the 0xFFFF-collision fix).
// ---------------------------------------------------------------------------
__global__ __launch_bounds__(256) void build_sched(
    const int* __restrict__ children,
    u16* __restrict__ wl,             // [65536] (b<<8)|t
    u32* __restrict__ lvl_start,      // [256]
    u32* __restrict__ lvl_cnt,        // [256]
    u32* __restrict__ nlev)           // [1]
{
    __shared__ unsigned char lvl[CB][CN];   // 64 KB
    __shared__ u32 cnt[CN];
    __shared__ u32 pos[CN];
    const int b = threadIdx.x;

    for (int t = 0; t < CN; ++t) {
        int lv = 0;
        #pragma unroll
        for (int k = 0; k < CK; ++k) {
            int raw = children[((size_t)b * CN + t) * CK + k];
            if (raw < t) { int cl = (int)lvl[b][raw] + 1; if (cl > lv) lv = cl; }
        }
        lvl[b][t] = (unsigned char)lv;
    }
    cnt[b] = 0;
    __syncthreads();
    for (int t = 0; t < CN; ++t) atomicAdd(&cnt[lvl[b][t]], 1u);
    __syncthreads();
    if (b == 0) {
        u32 acc = 0, nl = 0;
        for (int L = 0; L < CN; ++L) {
            pos[L] = acc;
            if (cnt[L]) nl = (u32)L + 1;
            acc += cnt[L];
        }
        *nlev = nl;
    }
    __syncthreads();
    lvl_cnt[b]   = cnt[b];
    lvl_start[b] = pos[b];
    __syncthreads();
    for (int t = 0; t < CN; ++t) {
        int L = lvl[b][t];
        u32 p = atomicAdd(&pos[L], 1u);
        wl[p] = (u16)((b << 8) | t);
    }
}

// ---------------------------------------------------------------------------
// r16: LEVEL-SCHEDULED persistent scan, 32-row chunks, packed-A, fused cell.
// Diagnosis (r14/r15 counters): runtime ∝ B-panel bytes streamed per chunk;
// B reuse = rows/chunk. Changes:
//  - A staged PACKED (hi16|lo16 u32 = h_pk format) -> both planes in one
//    32x1028 u32 LDS buffer (131.6 KB) -> 32-row chunks (2x B reuse).
//    h-stage becomes a straight u64 copy; x-stage packs in-register.
//  - wave = (rg in 2 row-groups) x (ctq in 4 col-groups) owns ALL 6 gate
//    planes of its 16 h-cols -> cell math in-lane on the verified D-layout
//    (col=l&15, row=(l>>4)*4+r). No part[] buffer, one less barrier.
//  - lo-correction chains merged into one accumulator (accL).
// 512 threads (8 waves, 2/SIMD, VGPR<=256 so no silent remat). S=4 slices,
// hi=(bid&7)>>1 XCD-affine; schedule/sc1/flag-barrier identical to r15.
// ---------------------------------------------------------------------------
__global__ __launch_bounds__(512, 2) void tree_scan_lvl(
    const int* __restrict__ node_ids,          // [B][N]
    const int* __restrict__ children,          // [B][N][K]
    const float* __restrict__ emb,             // [V][E]
    const u16* __restrict__ Whi,               // [1536][1024]
    const u16* __restrict__ Wlo,               // [1536][1024]
    const float* __restrict__ Wx_b,            // [G]
    const float* __restrict__ Uh_b,            // [K][G]
    u32* __restrict__ h_pk,                    // [N][B][H] u32 (hi16|lo16)
    float* __restrict__ c_s,                   // [N][B][H] f32
    u32* __restrict__ flags,                   // [256*16], zeroed per call
    const u16* __restrict__ wl,                // [65536]
    const u32* __restrict__ lvl_start,         // [256]
    const u32* __restrict__ lvl_cnt,           // [256]
    const u32* __restrict__ nlev_p,            // [1]
    float* __restrict__ out)                   // [B][H] f32
{
    const int tid = threadIdx.x;
    const int bid = blockIdx.x;
    const int hi  = (bid & 7) >> 1;                     // 0..3 (2 XCDs/slice)
    const int sub = ((bid >> 3) << 1) | (bid & 1);      // 0..63
    const int hh0 = hi * 64;

    __shared__ u32   Apk[ROWS][ASTRW];         // 131,584 B (hi|lo packed)
    __shared__ int   nid[ROWS], brow[ROWS], trow[ROWS];
    __shared__ unsigned char rval[ROWS];
    __shared__ float msk[ROWS][3];
    __shared__ int   cix[ROWS][3];

    const int wv    = tid >> 6;                // 0..7
    const int l     = tid & 63;
    const int rg    = wv >> 2;                 // 0..1 row-group
    const int ctq   = wv & 3;                  // 0..3 col-group (16 h-cols)
    const int lan15 = l & 15;
    const int k8w   = (l >> 4) * 8;            // k-offset (words/shorts)
    const int hcol  = hh0 + ctq * 16 + lan15;  // this lane's h column
    const int arow  = rg * 16 + lan15;         // this lane's A row

    // B row offsets for the 6 gate planes of hcol (u32 element offsets)
    u32 bb[6];
    #pragma unroll
    for (int q = 0; q < 6; ++q)
        bb[q] = (u32)(q * CH + hcol) * KTOT + k8w;

    const u32 NL = *nlev_p;

    for (u32 L = 0; L < NL; ++L) {
        const u32 lcnt   = lvl_cnt[L];
        const u32 lst    = lvl_start[L];
        const u32 nchunk = (lcnt + ROWS - 1) / ROWS;

        for (u32 ck = sub; ck < nchunk; ck += 64) {
            // per-task row setup; children re-derived from wl (no LDS dep,
            // so the tid<96 range may span waves safely)
            if (tid < ROWS) {
                u32 i = ck * ROWS + (u32)tid;
                int valid = (i < lcnt);
                u16 e = valid ? wl[lst + i] : (u16)0;
                rval[tid] = (unsigned char)valid;
                int b_ = valid ? (e >> 8) : 0;
                int t_ = valid ? (e & 0xFF) : 0;
                brow[tid] = b_;
                trow[tid] = t_;
                nid[tid]  = node_ids[(size_t)b_ * CN + t_];
            }
            if (tid < ROWS * CK) {
                int lb = tid / 3, k = tid - lb * 3;
                u32 i = ck * ROWS + (u32)lb;
                int valid = (i < lcnt);
                u16 e = valid ? wl[lst + i] : (u16)0;
                int b_ = valid ? (e >> 8) : 0;
                int t_ = valid ? (e & 0xFF) : 0;
                int raw = children[((size_t)b_ * CN + t_) * CK + k];
                int v = (raw < t_) && valid;
                msk[lb][k] = v ? 1.0f : 0.0f;
                cix[lb][k] = v ? raw : 0;
            }
            __syncthreads();

            // stage x: 32 rows x 64 float4; pack hi|lo in-register
            for (int idx = tid; idx < ROWS * 64; idx += 512) {
                int row = idx >> 6, c4 = idx & 63;
                float4v v = *(const float4v*)(emb + (size_t)nid[row] * CE + c4 * 4);
                uint4v p;
                #pragma unroll
                for (int j = 0; j < 4; ++j) {
                    u16 hb = f2bfu(v[j]);
                    u16 lb = f2bfu(v[j] - bfu2f(hb));
                    p[j] = ((u32)hb << 16) | (u32)lb;
                }
                *(uint4v*)&Apk[row][c4 * 4] = p;
            }
            // stage h: 96 (row,k) pairs x 128 u64 chunks — straight copy of
            // the packed h_pk format (sc1 agent-scope, r12-verified)
            for (int idx = tid; idx < ROWS * CK * 128; idx += 512) {
                int r  = idx >> 7;             // 0..95
                int ch = idx & 127;
                int row = r / 3, k = r - row * 3;
                u64 v = 0;
                if (msk[row][k] != 0.0f) {
                    const u64* src = (const u64*)(h_pk
                        + ((size_t)cix[row][k] * CB + brow[row]) * CH + 2 * ch);
                    v = __hip_atomic_load(src, __ATOMIC_RELAXED, __HIP_MEMORY_SCOPE_AGENT);
                }
                *(u64*)&Apk[row][CE + k * CH + 2 * ch] = v;
            }
            __syncthreads();

            // MFMA bf16x3 (lo-chains merged): 32 k-iters, 6 gate planes
            float4v accH[6], accL[6];
            #pragma unroll
            for (int q = 0; q < 6; ++q) {
                accH[q] = (float4v){0.f, 0.f, 0.f, 0.f};
                accL[q] = (float4v){0.f, 0.f, 0.f, 0.f};
            }
            #pragma unroll 4
            for (int ci = 0; ci < 32; ++ci) {
                uint4v a0 = *(const uint4v*)&Apk[arow][ci * 32 + k8w];
                uint4v a1 = *(const uint4v*)&Apk[arow][ci * 32 + k8w + 4];
                short8v ahi, alo;
                #pragma unroll
                for (int j = 0; j < 4; ++j) {
                    ahi[j]     = (short)(a0[j] >> 16);
                    alo[j]     = (short)(a0[j] & 0xffffu);
                    ahi[4 + j] = (short)(a1[j] >> 16);
                    alo[4 + j] = (short)(a1[j] & 0xffffu);
                }
                #pragma unroll
                for (int q = 0; q < 6; ++q) {
                    short8v bh = *(const short8v*)(Whi + bb[q] + ci * 32);
                    short8v bl = *(const short8v*)(Wlo + bb[q] + ci * 32);
                    accH[q] = __builtin_amdgcn_mfma_f32_16x16x32_bf16(ahi, bh, accH[q], 0, 0, 0);
                    accL[q] = __builtin_amdgcn_mfma_f32_16x16x32_bf16(ahi, bl, accL[q], 0, 0, 0);
                    accL[q] = __builtin_amdgcn_mfma_f32_16x16x32_bf16(alo, bh, accL[q], 0, 0, 0);
                }
            }

            // fused cell phase, in-lane on D-layout (col=l&15, row=(l>>4)*4+r)
            #pragma unroll
            for (int r = 0; r < 4; ++r) {
                const int row = rg * 16 + (l >> 4) * 4 + r;
                if (rval[row]) {
                    const int b = brow[row], t_ = trow[row];
                    const float m0 = msk[row][0], m1 = msk[row][1], m2 = msk[row][2];
                    float g[6];
                    #pragma unroll
                    for (int q = 0; q < 6; ++q) {
                        int gc = q * CH + hcol;
                        g[q] = accH[q][r] + accL[q][r]
                             + Wx_b[gc] + m0 * Uh_b[gc] + m1 * Uh_b[CG_ + gc]
                                        + m2 * Uh_b[2 * CG_ + gc];
                    }
                    float ig = 1.0f / (1.0f + expf(-g[0]));
                    float og = 1.0f / (1.0f + expf(-g[1]));
                    float ug = tanhf(g[2]);
                    float c = ig * ug;
                    if (m0 != 0.0f) c += (1.0f / (1.0f + expf(-g[3]))) *
                        __hip_atomic_load(&c_s[((size_t)cix[row][0] * CB + b) * CH + hcol],
                                          __ATOMIC_RELAXED, __HIP_MEMORY_SCOPE_AGENT);
                    if (m1 != 0.0f) c += (1.0f / (1.0f + expf(-g[4]))) *
                        __hip_atomic_load(&c_s[((size_t)cix[row][1] * CB + b) * CH + hcol],
                                          __ATOMIC_RELAXED, __HIP_MEMORY_SCOPE_AGENT);
                    if (m2 != 0.0f) c += (1.0f / (1.0f + expf(-g[5]))) *
                        __hip_atomic_load(&c_s[((size_t)cix[row][2] * CB + b) * CH + hcol],
                                          __ATOMIC_RELAXED, __HIP_MEMORY_SCOPE_AGENT);
                    float h = og * tanhf(c);
                    const size_t hx = ((size_t)t_ * CB + b) * CH + hcol;
                    u16 hb = f2bfu(h);
                    u32 hp = ((u32)hb << 16) | (u32)f2bfu(h - bfu2f(hb));
                    __hip_atomic_store(&h_pk[hx], hp, __ATOMIC_RELAXED, __HIP_MEMORY_SCOPE_AGENT);
                    __hip_atomic_store(&c_s[hx], c, __ATOMIC_RELAXED, __HIP_MEMORY_SCOPE_AGENT);
                    if (t_ == CN - 1) out[(size_t)b * CH + hcol] = h;
                }
            }
            __syncthreads();                   // Apk free before next stage
        }

        if (L == NL - 1) break;

        // ---- light grid barrier per level (r12/r14/r15-verified) ----
        __syncthreads();
        if (tid == 0)
            __hip_atomic_store(&flags[bid * 16], L + 1,
                               __ATOMIC_RELAXED, __HIP_MEMORY_SCOPE_AGENT);
        for (;;) {
            int ok = 1;
            if (tid < 256)
                ok = (__hip_atomic_load(&flags[tid * 16], __ATOMIC_RELAXED,
                                        __HIP_MEMORY_SCOPE_AGENT) >= L + 1);
            if (__syncthreads_and(ok)) break;
            __builtin_amdgcn_s_sleep(2);
        }
    }
}

// ---------------------------------------------------------------------------
// Fallback: r10-verified per-step MFMA kernel (used only if ws too small).
// ---------------------------------------------------------------------------
__global__ __launch_bounds__(768) void tree_step_mfma(
    const int* __restrict__ node_ids, const int* __restrict__ children,
    const float* __restrict__ emb,
    const u16* __restrict__ Whi, const u16* __restrict__ Wlo,
    const float* __restrict__ Wx_b, const float* __restrict__ Uh_b,
    u16* __restrict__ h_hi, u16* __restrict__ h_lo,
    float* __restrict__ c_s, float* __restrict__ out, const int t)
{
    const int tid = threadIdx.x;
    const int xcd  = blockIdx.x & 7;
    const int bidx = blockIdx.x >> 3;
    const int hi   = xcd * 2 + (bidx & 1);
    const int bi   = bidx >> 1;
    const int b0   = bi * 16;
    const int hh0  = hi * 16;

    __shared__ u16   Ahi[16][KTOT + 8];
    __shared__ u16   Alo[16][KTOT + 8];
    __shared__ float part[4][6][16][17];
    __shared__ int   nid[16];
    __shared__ float msk[16][3];
    __shared__ int   cix[16][3];

    const int wv    = tid >> 6;
    const int l     = tid & 63;
    const int np    = wv % 3;
    const int kq    = wv / 3;
    const int lan15 = l & 15;
    const int k8    = (l >> 4) * 8;

    if (tid < 16) nid[tid] = node_ids[(size_t)(b0 + tid) * CN + t];
    if (tid < 48) {
        int lb = tid / 3, k = tid - lb * 3;
        int raw = children[((size_t)(b0 + lb) * CN + t) * CK + k];
        int v = raw < t;
        msk[lb][k] = v ? 1.0f : 0.0f;
        cix[lb][k] = v ? raw : 0;
    }
    __syncthreads();

    for (int idx = tid; idx < 1024; idx += 768) {
        int lb = idx >> 6, c4 = idx & 63;
        float4v v = *(const float4v*)(emb + (size_t)nid[lb] * CE + c4 * 4);
        ushort4v h4, l4;
        #pragma unroll
        for (int j = 0; j < 4; ++j) {
            u16 hb = f2bfu(v[j]);
            h4[j] = hb;
            l4[j] = f2bfu(v[j] - bfu2f(hb));
        }
        *(ushort4v*)&Ahi[lb][c4 * 4] = h4;
        *(ushort4v*)&Alo[lb][c4 * 4] = l4;
    }
    for (int idx = tid; idx < 3072; idx += 768) {
        int r  = idx >> 6;
        int c  = idx & 63;
        int pl = c >> 5;
        int ch = c & 31;
        int lb = r / 3, k = r - lb * 3;
        uint4v val = (uint4v){0u, 0u, 0u, 0u};
        if (msk[lb][k] != 0.0f) {
            const u16* src = (pl ? h_lo : h_hi)
                + ((size_t)cix[lb][k] * CB + (b0 + lb)) * CH + ch * 8;
            val = *(const uint4v*)src;
        }
        u16* dst = (pl ? &Alo[lb][CE + k * CH + ch * 8]
                       : &Ahi[lb][CE + k * CH + ch * 8]);
        *(uint4v*)dst = val;
    }
    __syncthreads();

    {
        float4v acc[2][3];
        #pragma unroll
        for (int a = 0; a < 2; ++a)
            #pragma unroll
            for (int b2 = 0; b2 < 3; ++b2)
                acc[a][b2] = (float4v){0.f, 0.f, 0.f, 0.f};
        size_t bbase0 = (size_t)((np * 2 + 0) * CH + hh0 + lan15) * KTOT + k8;
        size_t bbase1 = (size_t)((np * 2 + 1) * CH + hh0 + lan15) * KTOT + k8;
        #pragma unroll
        for (int ci = 0; ci < 8; ++ci) {
            const int kb = (kq * 8 + ci) * 32 + k8;
            const int kbg = (kq * 8 + ci) * 32;
            short8v ahi = *(const short8v*)&Ahi[lan15][kb];
            short8v alo = *(const short8v*)&Alo[lan15][kb];
            short8v bh0 = *(const short8v*)(Whi + bbase0 + kbg);
            short8v bh1 = *(const short8v*)(Whi + bbase1 + kbg);
            short8v bl0 = *(const short8v*)(Wlo + bbase0 + kbg);
            short8v bl1 = *(const short8v*)(Wlo + bbase1 + kbg);
            acc[0][0] = __builtin_amdgcn_mfma_f32_16x16x32_bf16(ahi, bh0, acc[0][0], 0, 0, 0);
            acc[0][1] = __builtin_amdgcn_mfma_f32_16x16x32_bf16(ahi, bl0, acc[0][1], 0, 0, 0);
            acc[0][2] = __builtin_amdgcn_mfma_f32_16x16x32_bf16(alo, bh0, acc[0][2], 0, 0, 0);
            acc[1][0] = __builtin_amdgcn_mfma_f32_16x16x32_bf16(ahi, bh1, acc[1][0], 0, 0, 0);
            acc[1][1] = __builtin_amdgcn_mfma_f32_16x16x32_bf16(ahi, bl1, acc[1][1], 0, 0, 0);
            acc[1][2] = __builtin_amdgcn_mfma_f32_16x16x32_bf16(alo, bh1, acc[1][2], 0, 0, 0);
        }
        #pragma unroll
        for (int t2 = 0; t2 < 2; ++t2)
            #pragma unroll
            for (int r = 0; r < 4; ++r)
                part[kq][np * 2 + t2][(l >> 4) * 4 + r][lan15] =
                    acc[t2][0][r] + acc[t2][1][r] + acc[t2][2][r];
    }
    __syncthreads();

    if (tid < 256) {
        const int bb = tid >> 4, j2 = tid & 15;
        const int b = b0 + bb, hh = hh0 + j2;
        const float m0 = msk[bb][0], m1 = msk[bb][1], m2 = msk[bb][2];
        float g[6];
        #pragma unroll
        for (int q = 0; q < 6; ++q) {
            int gc = q * CH + hh;
            g[q] = part[0][q][bb][j2] + part[1][q][bb][j2]
                 + part[2][q][bb][j2] + part[3][q][bb][j2]
                 + Wx_b[gc] + m0 * Uh_b[gc] + m1 * Uh_b[CG_ + gc]
                            + m2 * Uh_b[2 * CG_ + gc];
        }
        float ig = 1.0f / (1.0f + expf(-g[0]));
        float og = 1.0f / (1.0f + expf(-g[1]));
        float ug = tanhf(g[2]);
        float c = ig * ug;
        if (m0 != 0.0f) c += (1.0f / (1.0f + expf(-g[3]))) * c_s[((size_t)cix[bb][0] * CB + b) * CH + hh];
        if (m1 != 0.0f) c += (1.0f / (1.0f + expf(-g[4]))) * c_s[((size_t)cix[bb][1] * CB + b) * CH + hh];
        if (m2 != 0.0f) c += (1.0f / (1.0f + expf(-g[5]))) * c_s[((size_t)cix[bb][2] * CB + b) * CH + hh];
        float h = og * tanhf(c);
        const size_t hx = ((size_t)t * CB + b) * CH + hh;
        u16 hb = f2bfu(h);
        h_hi[hx] = hb;
        h_lo[hx] = f2bfu(h - bfu2f(hb));
        c_s[hx] = c;
        if (t == CN - 1) out[(size_t)b * CH + hh] = h;
    }
}

__global__ void ws_report(float* out, int n, float val) {
    int i = blockIdx.x * blockDim.x + threadIdx.x;
    if (i < n) out[i] = val;
}

// ---------------------------------------------------------------------------
extern "C" void kernel_launch(void* const* d_in, const int* in_sizes, int n_in,
                              void* d_out, int out_size, void* d_ws, size_t ws_size,
                              hipStream_t stream) {
    float* outp = (float*)d_out;

    const int expect_sizes[7] = {65536, 196608, 8192000, 393216, 1536, 1179648, 4608};
    int bad = -1;
    if (n_in != 7) bad = 7;
    else for (int i = 0; i < 7; ++i) if (in_sizes[i] != expect_sizes[i]) { bad = i; break; }
    if (bad >= 0) {
        ws_report<<<(out_size + 255) / 256, 256, 0, stream>>>(outp, out_size, 1000.0f + bad);
        return;
    }

    const int*   node_ids = (const int*)d_in[0];
    const int*   children = (const int*)d_in[1];
    const float* emb      = (const float*)d_in[2];
    const float* Wx_w     = (const float*)d_in[3];
    const float* Wx_b     = (const float*)d_in[4];
    const float* Uh_w     = (const float*)d_in[5];
    const float* Uh_b     = (const float*)d_in[6];

    const size_t w_plane  = (size_t)CG_ * KTOT * 2;       //  3,145,728 B
    const size_t st_elems = (size_t)CN * CB * CH;         // 16,777,216
    const size_t flags_sz = 256 * 16 * sizeof(u32);       // 16 KB
    const size_t wl_sz    = (size_t)CB * CN * sizeof(u16);// 128 KB
    const size_t lvl_sz   = 256 * sizeof(u32);

    size_t off = 0;
    const size_t o_whi = off; off += w_plane;
    const size_t o_wlo = off; off += w_plane;
    const size_t o_hpk = off; off += st_elems * 4;
    const size_t o_cs  = off; off += st_elems * 4;
    const size_t o_flg = off; off += flags_sz;
    const size_t o_wl  = off; off += wl_sz;
    const size_t o_ls  = off; off += lvl_sz;
    const size_t o_lc  = off; off += lvl_sz;
    const size_t o_nl  = off; off += 64;
    const size_t need_lvl  = off;
    const size_t need_step = 2 * w_plane + st_elems * 2 * 2 + st_elems * 4;

    if (ws_size >= need_lvl) {
        char* w = (char*)d_ws;
        u16*   Whi = (u16*)(w + o_whi);
        u16*   Wlo = (u16*)(w + o_wlo);
        u32*   hpk = (u32*)(w + o_hpk);
        float* csb = (float*)(w + o_cs);
        u32*   flg = (u32*)(w + o_flg);
        u16*   wlp = (u16*)(w + o_wl);
        u32*   lsp = (u32*)(w + o_ls);
        u32*   lcp = (u32*)(w + o_lc);
        u32*   nlp = (u32*)(w + o_nl);

        prep_w<<<dim3(CG_), dim3(256), 0, stream>>>(Wx_w, Uh_w, Whi, Wlo);
        build_sched<<<dim3(1), dim3(256), 0, stream>>>(children, wlp, lsp, lcp, nlp);
        hipMemsetAsync(flg, 0, flags_sz, stream);

        void* args[] = { (void*)&node_ids, (void*)&children, (void*)&emb,
                         (void*)&Whi, (void*)&Wlo, (void*)&Wx_b, (void*)&Uh_b,
                         (void*)&hpk, (void*)&csb, (void*)&flg,
                         (void*)&wlp, (void*)&lsp, (void*)&lcp, (void*)&nlp,
                         (void*)&outp };
        hipError_t e = hipLaunchCooperativeKernel((const void*)tree_scan_lvl,
                                                  dim3(256), dim3(512), args, 0, stream);
        if (e == hipSuccess) return;
    }
    if (ws_size >= need_step) {
        char* w = (char*)d_ws;
        u16*   Whi = (u16*)w;
        u16*   Wlo = (u16*)(w + w_plane);
        u16*   hhi = (u16*)(w + 2 * w_plane);
        u16*   hlo = (u16*)(w + 2 * w_plane + st_elems * 2);
        float* csb = (float*)(w + 2 * w_plane + 2 * st_elems * 2);

        prep_w<<<dim3(CG_), dim3(256), 0, stream>>>(Wx_w, Uh_w, Whi, Wlo);
        for (int t = 0; t < CN; ++t)
            tree_step_mfma<<<dim3(256), dim3(768), 0, stream>>>(
                node_ids, children, emb, Whi, Wlo, Wx_b, Uh_b,
                hhi, hlo, csb, outp, t);
    } else {
        ws_report<<<(out_size + 255) / 256, 256, 0, stream>>>(
            outp, out_size, (float)(ws_size >> 20));
    }
}

// Round 17
// 2289.840 us; speedup vs baseline: 1.9543x; 1.9543x over previous
//
#include <hip/hip_runtime.h>
#include <hip/hip_bf16.h>

#define CB 256      // batch
#define CN 256      // nodes
#define CK 3        // children per node
#define CE 256      // embedding dim
#define CH 256      // hidden dim
#define CG_ 1536    // gates = 6*CH
#define KTOT 1024   // E + K*H
#define ROWS 32     // rows per chunk
#define ASTRW 1028  // Apk row stride in u32 words

typedef __attribute__((ext_vector_type(8))) short short8v;          // 8 bf16
typedef __attribute__((ext_vector_type(4))) float float4v;          // MFMA C/D
typedef __attribute__((ext_vector_type(4))) unsigned int uint4v;
typedef __attribute__((ext_vector_type(4))) unsigned short ushort4v;
typedef unsigned int u32;
typedef unsigned long long u64;
typedef unsigned short u16;

__device__ __forceinline__ u16 f2bfu(float v) {
    __hip_bfloat16 h = __float2bfloat16(v);
    return __builtin_bit_cast(u16, h);
}
__device__ __forceinline__ float bfu2f(u16 u) {
    __hip_bfloat16 h = __builtin_bit_cast(__hip_bfloat16, u);
    return __bfloat162float(h);
}

// ---------------------------------------------------------------------------
// Prep r17: split W = [Wx_w ; Uh_w] (1024 x 1536) into bf16 hi/lo planes in
// MFMA-FRAGMENT order: [tile(16 gate cols)][ci(32k-chunk)][lane 0..63][8 bf16]
// where lane l holds col tile*16+(l&15), k = ci*32+(l>>4)*8+j.
// A wave's B-load becomes 1 KB fully contiguous (r16's K-major layout made
// every wave B-load a 16-cache-line gather 2 KB apart -> ~28 GB/s/CU, the
// measured r14/r15/r16 wall: T_chunk ~ 33-40 us per MB of B).
// ---------------------------------------------------------------------------
__global__ __launch_bounds__(256) void prep_w(
    const float* __restrict__ Wx_w, const float* __restrict__ Uh_w,
    u16* __restrict__ Whi, u16* __restrict__ Wlo)
{
    const int g    = blockIdx.x;           // gate col 0..1535
    const int tile = g >> 4;
    const int gl   = g & 15;
    for (int k = threadIdx.x; k < KTOT; k += 256) {
        float w = (k < CE) ? Wx_w[(size_t)k * CG_ + g]
                           : Uh_w[(size_t)(k - CE) * CG_ + g];
        u16 hi = f2bfu(w);
        u16 lo = f2bfu(w - bfu2f(hi));
        int ci = k >> 5, kr = k & 31, lq = kr >> 3, j = kr & 7;
        size_t idx = ((size_t)(tile * 32 + ci) * 64 + lq * 16 + gl) * 8 + j;
        Whi[idx] = hi;
        Wlo[idx] = lo;
    }
}

// ---------------------------------------------------------------------------
// Level schedule build (verified r14-r16, incl. the 0xFFFF-collision fix).
// ---------------------------------------------------------------------------
__global__ __launch_bounds__(256) void build_sched(
    const int* __restrict__ children,
    u16* __restrict__ wl,             // [65536] (b<<8)|t
    u32* __restrict__ lvl_start,      // [256]
    u32* __restrict__ lvl_cnt,        // [256]
    u32* __restrict__ nlev)           // [1]
{
    __shared__ unsigned char lvl[CB][CN];   // 64 KB
    __shared__ u32 cnt[CN];
    __shared__ u32 pos[CN];
    const int b = threadIdx.x;

    for (int t = 0; t < CN; ++t) {
        int lv = 0;
        #pragma unroll
        for (int k = 0; k < CK; ++k) {
            int raw = children[((size_t)b * CN + t) * CK + k];
            if (raw < t) { int cl = (int)lvl[b][raw] + 1; if (cl > lv) lv = cl; }
        }
        lvl[b][t] = (unsigned char)lv;
    }
    cnt[b] = 0;
    __syncthreads();
    for (int t = 0; t < CN; ++t) atomicAdd(&cnt[lvl[b][t]], 1u);
    __syncthreads();
    if (b == 0) {
        u32 acc = 0, nl = 0;
        for (int L = 0; L < CN; ++L) {
            pos[L] = acc;
            if (cnt[L]) nl = (u32)L + 1;
            acc += cnt[L];
        }
        *nlev = nl;
    }
    __syncthreads();
    lvl_cnt[b]   = cnt[b];
    lvl_start[b] = pos[b];
    __syncthreads();
    for (int t = 0; t < CN; ++t) {
        int L = lvl[b][t];
        u32 p = atomicAdd(&pos[L], 1u);
        wl[p] = (u16)((b << 8) | t);
    }
}

// ---------------------------------------------------------------------------
// r17 scan: identical structure/math to r16 (passed, absmax 1.22e-4); the
// ONLY change is B addressing into the fragment-ordered planes.
// ---------------------------------------------------------------------------
__global__ __launch_bounds__(512, 2) void tree_scan_lvl(
    const int* __restrict__ node_ids,          // [B][N]
    const int* __restrict__ children,          // [B][N][K]
    const float* __restrict__ emb,             // [V][E]
    const u16* __restrict__ Whi,               // fragment-ordered
    const u16* __restrict__ Wlo,               // fragment-ordered
    const float* __restrict__ Wx_b,            // [G]
    const float* __restrict__ Uh_b,            // [K][G]
    u32* __restrict__ h_pk,                    // [N][B][H] u32 (hi16|lo16)
    float* __restrict__ c_s,                   // [N][B][H] f32
    u32* __restrict__ flags,                   // [256*16], zeroed per call
    const u16* __restrict__ wl,                // [65536]
    const u32* __restrict__ lvl_start,         // [256]
    const u32* __restrict__ lvl_cnt,           // [256]
    const u32* __restrict__ nlev_p,            // [1]
    float* __restrict__ out)                   // [B][H] f32
{
    const int tid = threadIdx.x;
    const int bid = blockIdx.x;
    const int hi  = (bid & 7) >> 1;                     // 0..3 (2 XCDs/slice)
    const int sub = ((bid >> 3) << 1) | (bid & 1);      // 0..63
    const int hh0 = hi * 64;

    __shared__ u32   Apk[ROWS][ASTRW];         // 131,584 B (hi|lo packed)
    __shared__ int   nid[ROWS], brow[ROWS], trow[ROWS];
    __shared__ unsigned char rval[ROWS];
    __shared__ float msk[ROWS][3];
    __shared__ int   cix[ROWS][3];

    const int wv    = tid >> 6;                // 0..7
    const int l     = tid & 63;
    const int rg    = wv >> 2;                 // 0..1 row-group
    const int ctq   = wv & 3;                  // 0..3 col-group (16 h-cols)
    const int lan15 = l & 15;
    const int k8w   = (l >> 4) * 8;            // k-offset inside A row
    const int hcol  = hh0 + ctq * 16 + lan15;  // this lane's h column
    const int arow  = rg * 16 + lan15;         // this lane's A row

    // fragment-plane bases for the 6 gate planes of this wave's col-tile:
    // tile = q*16 + hh0/16 + ctq; addr = tile*16384 + l*8 (+ ci*512)
    u32 bb[6];
    #pragma unroll
    for (int q = 0; q < 6; ++q)
        bb[q] = (u32)(q * 16 + (hh0 >> 4) + ctq) * 16384u + (u32)l * 8u;

    const u32 NL = *nlev_p;

    for (u32 L = 0; L < NL; ++L) {
        const u32 lcnt   = lvl_cnt[L];
        const u32 lst    = lvl_start[L];
        const u32 nchunk = (lcnt + ROWS - 1) / ROWS;

        for (u32 ck = sub; ck < nchunk; ck += 64) {
            if (tid < ROWS) {
                u32 i = ck * ROWS + (u32)tid;
                int valid = (i < lcnt);
                u16 e = valid ? wl[lst + i] : (u16)0;
                rval[tid] = (unsigned char)valid;
                int b_ = valid ? (e >> 8) : 0;
                int t_ = valid ? (e & 0xFF) : 0;
                brow[tid] = b_;
                trow[tid] = t_;
                nid[tid]  = node_ids[(size_t)b_ * CN + t_];
            }
            if (tid < ROWS * CK) {
                int lb = tid / 3, k = tid - lb * 3;
                u32 i = ck * ROWS + (u32)lb;
                int valid = (i < lcnt);
                u16 e = valid ? wl[lst + i] : (u16)0;
                int b_ = valid ? (e >> 8) : 0;
                int t_ = valid ? (e & 0xFF) : 0;
                int raw = children[((size_t)b_ * CN + t_) * CK + k];
                int v = (raw < t_) && valid;
                msk[lb][k] = v ? 1.0f : 0.0f;
                cix[lb][k] = v ? raw : 0;
            }
            __syncthreads();

            // stage x: 32 rows x 64 float4; pack hi|lo in-register
            for (int idx = tid; idx < ROWS * 64; idx += 512) {
                int row = idx >> 6, c4 = idx & 63;
                float4v v = *(const float4v*)(emb + (size_t)nid[row] * CE + c4 * 4);
                uint4v p;
                #pragma unroll
                for (int j = 0; j < 4; ++j) {
                    u16 hb = f2bfu(v[j]);
                    u16 lb = f2bfu(v[j] - bfu2f(hb));
                    p[j] = ((u32)hb << 16) | (u32)lb;
                }
                *(uint4v*)&Apk[row][c4 * 4] = p;
            }
            // stage h: straight copy of packed h_pk (sc1 agent-scope)
            for (int idx = tid; idx < ROWS * CK * 128; idx += 512) {
                int r  = idx >> 7;             // 0..95
                int ch = idx & 127;
                int row = r / 3, k = r - row * 3;
                u64 v = 0;
                if (msk[row][k] != 0.0f) {
                    const u64* src = (const u64*)(h_pk
                        + ((size_t)cix[row][k] * CB + brow[row]) * CH + 2 * ch);
                    v = __hip_atomic_load(src, __ATOMIC_RELAXED, __HIP_MEMORY_SCOPE_AGENT);
                }
                *(u64*)&Apk[row][CE + k * CH + 2 * ch] = v;
            }
            __syncthreads();

            // MFMA bf16x3: 32 k-iters, 6 gate planes; B loads now 1 KB
            // contiguous per wave instruction (fragment-ordered planes)
            float4v accH[6], accL[6];
            #pragma unroll
            for (int q = 0; q < 6; ++q) {
                accH[q] = (float4v){0.f, 0.f, 0.f, 0.f};
                accL[q] = (float4v){0.f, 0.f, 0.f, 0.f};
            }
            #pragma unroll 4
            for (int ci = 0; ci < 32; ++ci) {
                uint4v a0 = *(const uint4v*)&Apk[arow][ci * 32 + k8w];
                uint4v a1 = *(const uint4v*)&Apk[arow][ci * 32 + k8w + 4];
                short8v ahi, alo;
                #pragma unroll
                for (int j = 0; j < 4; ++j) {
                    ahi[j]     = (short)(a0[j] >> 16);
                    alo[j]     = (short)(a0[j] & 0xffffu);
                    ahi[4 + j] = (short)(a1[j] >> 16);
                    alo[4 + j] = (short)(a1[j] & 0xffffu);
                }
                #pragma unroll
                for (int q = 0; q < 6; ++q) {
                    short8v bh = *(const short8v*)(Whi + bb[q] + ci * 512);
                    short8v bl = *(const short8v*)(Wlo + bb[q] + ci * 512);
                    accH[q] = __builtin_amdgcn_mfma_f32_16x16x32_bf16(ahi, bh, accH[q], 0, 0, 0);
                    accL[q] = __builtin_amdgcn_mfma_f32_16x16x32_bf16(ahi, bl, accL[q], 0, 0, 0);
                    accL[q] = __builtin_amdgcn_mfma_f32_16x16x32_bf16(alo, bh, accL[q], 0, 0, 0);
                }
            }

            // fused cell phase, in-lane on D-layout (col=l&15, row=(l>>4)*4+r)
            #pragma unroll
            for (int r = 0; r < 4; ++r) {
                const int row = rg * 16 + (l >> 4) * 4 + r;
                if (rval[row]) {
                    const int b = brow[row], t_ = trow[row];
                    const float m0 = msk[row][0], m1 = msk[row][1], m2 = msk[row][2];
                    float g[6];
                    #pragma unroll
                    for (int q = 0; q < 6; ++q) {
                        int gc = q * CH + hcol;
                        g[q] = accH[q][r] + accL[q][r]
                             + Wx_b[gc] + m0 * Uh_b[gc] + m1 * Uh_b[CG_ + gc]
                                        + m2 * Uh_b[2 * CG_ + gc];
                    }
                    float ig = 1.0f / (1.0f + expf(-g[0]));
                    float og = 1.0f / (1.0f + expf(-g[1]));
                    float ug = tanhf(g[2]);
                    float c = ig * ug;
                    if (m0 != 0.0f) c += (1.0f / (1.0f + expf(-g[3]))) *
                        __hip_atomic_load(&c_s[((size_t)cix[row][0] * CB + b) * CH + hcol],
                                          __ATOMIC_RELAXED, __HIP_MEMORY_SCOPE_AGENT);
                    if (m1 != 0.0f) c += (1.0f / (1.0f + expf(-g[4]))) *
                        __hip_atomic_load(&c_s[((size_t)cix[row][1] * CB + b) * CH + hcol],
                                          __ATOMIC_RELAXED, __HIP_MEMORY_SCOPE_AGENT);
                    if (m2 != 0.0f) c += (1.0f / (1.0f + expf(-g[5]))) *
                        __hip_atomic_load(&c_s[((size_t)cix[row][2] * CB + b) * CH + hcol],
                                          __ATOMIC_RELAXED, __HIP_MEMORY_SCOPE_AGENT);
                    float h = og * tanhf(c);
                    const size_t hx = ((size_t)t_ * CB + b) * CH + hcol;
                    u16 hb = f2bfu(h);
                    u32 hp = ((u32)hb << 16) | (u32)f2bfu(h - bfu2f(hb));
                    __hip_atomic_store(&h_pk[hx], hp, __ATOMIC_RELAXED, __HIP_MEMORY_SCOPE_AGENT);
                    __hip_atomic_store(&c_s[hx], c, __ATOMIC_RELAXED, __HIP_MEMORY_SCOPE_AGENT);
                    if (t_ == CN - 1) out[(size_t)b * CH + hcol] = h;
                }
            }
            __syncthreads();                   // Apk free before next stage
        }

        if (L == NL - 1) break;

        // ---- light grid barrier per level (r12/r14-r16 verified) ----
        __syncthreads();
        if (tid == 0)
            __hip_atomic_store(&flags[bid * 16], L + 1,
                               __ATOMIC_RELAXED, __HIP_MEMORY_SCOPE_AGENT);
        for (;;) {
            int ok = 1;
            if (tid < 256)
                ok = (__hip_atomic_load(&flags[tid * 16], __ATOMIC_RELAXED,
                                        __HIP_MEMORY_SCOPE_AGENT) >= L + 1);
            if (__syncthreads_and(ok)) break;
            __builtin_amdgcn_s_sleep(2);
        }
    }
}

// ---------------------------------------------------------------------------
// Fallback: r10-verified per-step kernel, updated to fragment-ordered B
// (tile = (np*2+t2)*16 + hi; k-chunk = kq*8+ci).
// ---------------------------------------------------------------------------
__global__ __launch_bounds__(768) void tree_step_mfma(
    const int* __restrict__ node_ids, const int* __restrict__ children,
    const float* __restrict__ emb,
    const u16* __restrict__ Whi, const u16* __restrict__ Wlo,
    const float* __restrict__ Wx_b, const float* __restrict__ Uh_b,
    u16* __restrict__ h_hi, u16* __restrict__ h_lo,
    float* __restrict__ c_s, float* __restrict__ out, const int t)
{
    const int tid = threadIdx.x;
    const int xcd  = blockIdx.x & 7;
    const int bidx = blockIdx.x >> 3;
    const int hi   = xcd * 2 + (bidx & 1);
    const int bi   = bidx >> 1;
    const int b0   = bi * 16;
    const int hh0  = hi * 16;

    __shared__ u16   Ahi[16][KTOT + 8];
    __shared__ u16   Alo[16][KTOT + 8];
    __shared__ float part[4][6][16][17];
    __shared__ int   nid[16];
    __shared__ float msk[16][3];
    __shared__ int   cix[16][3];

    const int wv    = tid >> 6;
    const int l     = tid & 63;
    const int np    = wv % 3;
    const int kq    = wv / 3;
    const int lan15 = l & 15;
    const int k8    = (l >> 4) * 8;

    if (tid < 16) nid[tid] = node_ids[(size_t)(b0 + tid) * CN + t];
    if (tid < 48) {
        int lb = tid / 3, k = tid - lb * 3;
        int raw = children[((size_t)(b0 + lb) * CN + t) * CK + k];
        int v = raw < t;
        msk[lb][k] = v ? 1.0f : 0.0f;
        cix[lb][k] = v ? raw : 0;
    }
    __syncthreads();

    for (int idx = tid; idx < 1024; idx += 768) {
        int lb = idx >> 6, c4 = idx & 63;
        float4v v = *(const float4v*)(emb + (size_t)nid[lb] * CE + c4 * 4);
        ushort4v h4, l4;
        #pragma unroll
        for (int j = 0; j < 4; ++j) {
            u16 hb = f2bfu(v[j]);
            h4[j] = hb;
            l4[j] = f2bfu(v[j] - bfu2f(hb));
        }
        *(ushort4v*)&Ahi[lb][c4 * 4] = h4;
        *(ushort4v*)&Alo[lb][c4 * 4] = l4;
    }
    for (int idx = tid; idx < 3072; idx += 768) {
        int r  = idx >> 6;
        int c  = idx & 63;
        int pl = c >> 5;
        int ch = c & 31;
        int lb = r / 3, k = r - lb * 3;
        uint4v val = (uint4v){0u, 0u, 0u, 0u};
        if (msk[lb][k] != 0.0f) {
            const u16* src = (pl ? h_lo : h_hi)
                + ((size_t)cix[lb][k] * CB + (b0 + lb)) * CH + ch * 8;
            val = *(const uint4v*)src;
        }
        u16* dst = (pl ? &Alo[lb][CE + k * CH + ch * 8]
                       : &Ahi[lb][CE + k * CH + ch * 8]);
        *(uint4v*)dst = val;
    }
    __syncthreads();

    {
        float4v acc[2][3];
        #pragma unroll
        for (int a = 0; a < 2; ++a)
            #pragma unroll
            for (int b2 = 0; b2 < 3; ++b2)
                acc[a][b2] = (float4v){0.f, 0.f, 0.f, 0.f};
        u32 fb0 = (u32)((np * 2 + 0) * 16 + hi) * 16384u + (u32)l * 8u;
        u32 fb1 = (u32)((np * 2 + 1) * 16 + hi) * 16384u + (u32)l * 8u;
        #pragma unroll
        for (int ci = 0; ci < 8; ++ci) {
            const int kb = (kq * 8 + ci) * 32 + k8;
            const u32 fo = (u32)(kq * 8 + ci) * 512u;
            short8v ahi = *(const short8v*)&Ahi[lan15][kb];
            short8v alo = *(const short8v*)&Alo[lan15][kb];
            short8v bh0 = *(const short8v*)(Whi + fb0 + fo);
            short8v bh1 = *(const short8v*)(Whi + fb1 + fo);
            short8v bl0 = *(const short8v*)(Wlo + fb0 + fo);
            short8v bl1 = *(const short8v*)(Wlo + fb1 + fo);
            acc[0][0] = __builtin_amdgcn_mfma_f32_16x16x32_bf16(ahi, bh0, acc[0][0], 0, 0, 0);
            acc[0][1] = __builtin_amdgcn_mfma_f32_16x16x32_bf16(ahi, bl0, acc[0][1], 0, 0, 0);
            acc[0][2] = __builtin_amdgcn_mfma_f32_16x16x32_bf16(alo, bh0, acc[0][2], 0, 0, 0);
            acc[1][0] = __builtin_amdgcn_mfma_f32_16x16x32_bf16(ahi, bh1, acc[1][0], 0, 0, 0);
            acc[1][1] = __builtin_amdgcn_mfma_f32_16x16x32_bf16(ahi, bl1, acc[1][1], 0, 0, 0);
            acc[1][2] = __builtin_amdgcn_mfma_f32_16x16x32_bf16(alo, bh1, acc[1][2], 0, 0, 0);
        }
        #pragma unroll
        for (int t2 = 0; t2 < 2; ++t2)
            #pragma unroll
            for (int r = 0; r < 4; ++r)
                part[kq][np * 2 + t2][(l >> 4) * 4 + r][lan15] =
                    acc[t2][0][r] + acc[t2][1][r] + acc[t2][2][r];
    }
    __syncthreads();

    if (tid < 256) {
        const int bb = tid >> 4, j2 = tid & 15;
        const int b = b0 + bb, hh = hh0 + j2;
        const float m0 = msk[bb][0], m1 = msk[bb][1], m2 = msk[bb][2];
        float g[6];
        #pragma unroll
        for (int q = 0; q < 6; ++q) {
            int gc = q * CH + hh;
            g[q] = part[0][q][bb][j2] + part[1][q][bb][j2]
                 + part[2][q][bb][j2] + part[3][q][bb][j2]
                 + Wx_b[gc] + m0 * Uh_b[gc] + m1 * Uh_b[CG_ + gc]
                            + m2 * Uh_b[2 * CG_ + gc];
        }
        float ig = 1.0f / (1.0f + expf(-g[0]));
        float og = 1.0f / (1.0f + expf(-g[1]));
        float ug = tanhf(g[2]);
        float c = ig * ug;
        if (m0 != 0.0f) c += (1.0f / (1.0f + expf(-g[3]))) * c_s[((size_t)cix[bb][0] * CB + b) * CH + hh];
        if (m1 != 0.0f) c += (1.0f / (1.0f + expf(-g[4]))) * c_s[((size_t)cix[bb][1] * CB + b) * CH + hh];
        if (m2 != 0.0f) c += (1.0f / (1.0f + expf(-g[5]))) * c_s[((size_t)cix[bb][2] * CB + b) * CH + hh];
        float h = og * tanhf(c);
        const size_t hx = ((size_t)t * CB + b) * CH + hh;
        u16 hb = f2bfu(h);
        h_hi[hx] = hb;
        h_lo[hx] = f2bfu(h - bfu2f(hb));
        c_s[hx] = c;
        if (t == CN - 1) out[(size_t)b * CH + hh] = h;
    }
}

__global__ void ws_report(float* out, int n, float val) {
    int i = blockIdx.x * blockDim.x + threadIdx.x;
    if (i < n) out[i] = val;
}

// ---------------------------------------------------------------------------
extern "C" void kernel_launch(void* const* d_in, const int* in_sizes, int n_in,
                              void* d_out, int out_size, void* d_ws, size_t ws_size,
                              hipStream_t stream) {
    float* outp = (float*)d_out;

    const int expect_sizes[7] = {65536, 196608, 8192000, 393216, 1536, 1179648, 4608};
    int bad = -1;
    if (n_in != 7) bad = 7;
    else for (int i = 0; i < 7; ++i) if (in_sizes[i] != expect_sizes[i]) { bad = i; break; }
    if (bad >= 0) {
        ws_report<<<(out_size + 255) / 256, 256, 0, stream>>>(outp, out_size, 1000.0f + bad);
        return;
    }

    const int*   node_ids = (const int*)d_in[0];
    const int*   children = (const int*)d_in[1];
    const float* emb      = (const float*)d_in[2];
    const float* Wx_w     = (const float*)d_in[3];
    const float* Wx_b     = (const float*)d_in[4];
    const float* Uh_w     = (const float*)d_in[5];
    const float* Uh_b     = (const float*)d_in[6];

    const size_t w_plane  = (size_t)CG_ * KTOT * 2;       //  3,145,728 B
    const size_t st_elems = (size_t)CN * CB * CH;         // 16,777,216
    const size_t flags_sz = 256 * 16 * sizeof(u32);       // 16 KB
    const size_t wl_sz    = (size_t)CB * CN * sizeof(u16);// 128 KB
    const size_t lvl_sz   = 256 * sizeof(u32);

    size_t off = 0;
    const size_t o_whi = off; off += w_plane;
    const size_t o_wlo = off; off += w_plane;
    const size_t o_hpk = off; off += st_elems * 4;
    const size_t o_cs  = off; off += st_elems * 4;
    const size_t o_flg = off; off += flags_sz;
    const size_t o_wl  = off; off += wl_sz;
    const size_t o_ls  = off; off += lvl_sz;
    const size_t o_lc  = off; off += lvl_sz;
    const size_t o_nl  = off; off += 64;
    const size_t need_lvl  = off;
    const size_t need_step = 2 * w_plane + st_elems * 2 * 2 + st_elems * 4;

    if (ws_size >= need_lvl) {
        char* w = (char*)d_ws;
        u16*   Whi = (u16*)(w + o_whi);
        u16*   Wlo = (u16*)(w + o_wlo);
        u32*   hpk = (u32*)(w + o_hpk);
        float* csb = (float*)(w + o_cs);
        u32*   flg = (u32*)(w + o_flg);
        u16*   wlp = (u16*)(w + o_wl);
        u32*   lsp = (u32*)(w + o_ls);
        u32*   lcp = (u32*)(w + o_lc);
        u32*   nlp = (u32*)(w + o_nl);

        prep_w<<<dim3(CG_), dim3(256), 0, stream>>>(Wx_w, Uh_w, Whi, Wlo);
        build_sched<<<dim3(1), dim3(256), 0, stream>>>(children, wlp, lsp, lcp, nlp);
        hipMemsetAsync(flg, 0, flags_sz, stream);

        void* args[] = { (void*)&node_ids, (void*)&children, (void*)&emb,
                         (void*)&Whi, (void*)&Wlo, (void*)&Wx_b, (void*)&Uh_b,
                         (void*)&hpk, (void*)&csb, (void*)&flg,
                         (void*)&wlp, (void*)&lsp, (void*)&lcp, (void*)&nlp,
                         (void*)&outp };
        hipError_t e = hipLaunchCooperativeKernel((const void*)tree_scan_lvl,
                                                  dim3(256), dim3(512), args, 0, stream);
        if (e == hipSuccess) return;
    }
    if (ws_size >= need_step) {
        char* w = (char*)d_ws;
        u16*   Whi = (u16*)w;
        u16*   Wlo = (u16*)(w + w_plane);
        u16*   hhi = (u16*)(w + 2 * w_plane);
        u16*   hlo = (u16*)(w + 2 * w_plane + st_elems * 2);
        float* csb = (float*)(w + 2 * w_plane + 2 * st_elems * 2);

        prep_w<<<dim3(CG_), dim3(256), 0, stream>>>(Wx_w, Uh_w, Whi, Wlo);
        for (int t = 0; t < CN; ++t)
            tree_step_mfma<<<dim3(256), dim3(768), 0, stream>>>(
                node_ids, children, emb, Whi, Wlo, Wx_b, Uh_b,
                hhi, hlo, csb, outp, t);
    } else {
        ws_report<<<(out_size + 255) / 256, 256, 0, stream>>>(
            outp, out_size, (float)(ws_size >> 20));
    }
}

// Round 18
// 2105.726 us; speedup vs baseline: 2.1251x; 1.0874x over previous
//
#include <hip/hip_runtime.h>
#include <hip/hip_bf16.h>

#define CB 256      // batch
#define CN 256      // nodes
#define CK 3        // children per node
#define CE 256      // embedding dim
#define CH 256      // hidden dim
#define CG_ 1536    // gates = 6*CH
#define KTOT 1024   // E + K*H
#define ROWS 32     // rows per chunk
#define ASTRW 1028  // Apk row stride in u32 words

typedef __attribute__((ext_vector_type(8))) short short8v;          // 8 bf16
typedef __attribute__((ext_vector_type(4))) float float4v;          // MFMA C/D
typedef __attribute__((ext_vector_type(4))) unsigned int uint4v;
typedef __attribute__((ext_vector_type(4))) unsigned short ushort4v;
typedef unsigned int u32;
typedef unsigned long long u64;
typedef unsigned short u16;

__device__ __forceinline__ u16 f2bfu(float v) {
    __hip_bfloat16 h = __float2bfloat16(v);
    return __builtin_bit_cast(u16, h);
}
__device__ __forceinline__ float bfu2f(u16 u) {
    __hip_bfloat16 h = __builtin_bit_cast(__hip_bfloat16, u);
    return __bfloat162float(h);
}

// ---------------------------------------------------------------------------
// Prep (verified r17): split W = [Wx_w ; Uh_w] into bf16 hi/lo planes in
// MFMA-FRAGMENT order [tile(16 gate cols)][ci][lane][8] — wave B-load = 1 KB
// contiguous (the r17 2x win).
// ---------------------------------------------------------------------------
__global__ __launch_bounds__(256) void prep_w(
    const float* __restrict__ Wx_w, const float* __restrict__ Uh_w,
    u16* __restrict__ Whi, u16* __restrict__ Wlo)
{
    const int g    = blockIdx.x;           // gate col 0..1535
    const int tile = g >> 4;
    const int gl   = g & 15;
    for (int k = threadIdx.x; k < KTOT; k += 256) {
        float w = (k < CE) ? Wx_w[(size_t)k * CG_ + g]
                           : Uh_w[(size_t)(k - CE) * CG_ + g];
        u16 hi = f2bfu(w);
        u16 lo = f2bfu(w - bfu2f(hi));
        int ci = k >> 5, kr = k & 31, lq = kr >> 3, j = kr & 7;
        size_t idx = ((size_t)(tile * 32 + ci) * 64 + lq * 16 + gl) * 8 + j;
        Whi[idx] = hi;
        Wlo[idx] = lo;
    }
}

// ---------------------------------------------------------------------------
// Level schedule build (verified r14-r17, incl. the 0xFFFF-collision fix).
// ---------------------------------------------------------------------------
__global__ __launch_bounds__(256) void build_sched(
    const int* __restrict__ children,
    u16* __restrict__ wl,             // [65536] (b<<8)|t
    u32* __restrict__ lvl_start,      // [256]
    u32* __restrict__ lvl_cnt,        // [256]
    u32* __restrict__ nlev)           // [1]
{
    __shared__ unsigned char lvl[CB][CN];   // 64 KB
    __shared__ u32 cnt[CN];
    __shared__ u32 pos[CN];
    const int b = threadIdx.x;

    for (int t = 0; t < CN; ++t) {
        int lv = 0;
        #pragma unroll
        for (int k = 0; k < CK; ++k) {
            int raw = children[((size_t)b * CN + t) * CK + k];
            if (raw < t) { int cl = (int)lvl[b][raw] + 1; if (cl > lv) lv = cl; }
        }
        lvl[b][t] = (unsigned char)lv;
    }
    cnt[b] = 0;
    __syncthreads();
    for (int t = 0; t < CN; ++t) atomicAdd(&cnt[lvl[b][t]], 1u);
    __syncthreads();
    if (b == 0) {
        u32 acc = 0, nl = 0;
        for (int L = 0; L < CN; ++L) {
            pos[L] = acc;
            if (cnt[L]) nl = (u32)L + 1;
            acc += cnt[L];
        }
        *nlev = nl;
    }
    __syncthreads();
    lvl_cnt[b]   = cnt[b];
    lvl_start[b] = pos[b];
    __syncthreads();
    for (int t = 0; t < CN; ++t) {
        int L = lvl[b][t];
        u32 p = atomicAdd(&pos[L], 1u);
        wl[p] = (u16)((b << 8) | t);
    }
}

// ---------------------------------------------------------------------------
// r18 scan: S=2 slices (128 H-cols/block) + wave-level B reuse across BOTH
// row-groups. r17 budget: ~65 us/chunk = B 3MB (~22) + gather 96KB sc1 (~15)
// + x/cell (~10) + MFMA 2.4; intra-block B was 2x-redundant (rg waves) and
// gathers 4x-replicated (S=4). This round: 8 waves = 8 distinct col-tiles,
// each wave computes rg0+rg1 with ONE B fragment load (zero B redundancy);
// S=2 halves gather replication. Totals: B 24.6->12.3 GB, gather 786->393 MB.
// Per ci: 12 B-loads : 72 MFMA -> B mostly hidden under the matrix pipe.
// All schedule/sc1/flag-barrier machinery identical to r17 (verified).
// ---------------------------------------------------------------------------
__global__ __launch_bounds__(512, 2) void tree_scan_lvl(
    const int* __restrict__ node_ids,          // [B][N]
    const int* __restrict__ children,          // [B][N][K]
    const float* __restrict__ emb,             // [V][E]
    const u16* __restrict__ Whi,               // fragment-ordered
    const u16* __restrict__ Wlo,               // fragment-ordered
    const float* __restrict__ Wx_b,            // [G]
    const float* __restrict__ Uh_b,            // [K][G]
    u32* __restrict__ h_pk,                    // [N][B][H] u32 (hi16|lo16)
    float* __restrict__ c_s,                   // [N][B][H] f32
    u32* __restrict__ flags,                   // [256*16], zeroed per call
    const u16* __restrict__ wl,                // [65536]
    const u32* __restrict__ lvl_start,         // [256]
    const u32* __restrict__ lvl_cnt,           // [256]
    const u32* __restrict__ nlev_p,            // [1]
    float* __restrict__ out)                   // [B][H] f32
{
    const int tid = threadIdx.x;
    const int bid = blockIdx.x;
    const int xcd   = bid & 7;
    const int slice = xcd >> 2;                          // 0..1 (4 XCDs each)
    const int sub   = ((bid >> 3) << 2) | (bid & 3);     // 0..127
    const int hh0   = slice * 128;

    __shared__ u32   Apk[ROWS][ASTRW];         // 131,584 B (hi|lo packed)
    __shared__ int   nid[ROWS], brow[ROWS], trow[ROWS];
    __shared__ unsigned char rval[ROWS];
    __shared__ float msk[ROWS][3];
    __shared__ int   cix[ROWS][3];

    const int wv    = tid >> 6;                // 0..7 = col-tile (ctq)
    const int l     = tid & 63;
    const int lan15 = l & 15;
    const int k8w   = (l >> 4) * 8;            // k-offset inside A row
    const int hcol  = hh0 + wv * 16 + lan15;   // this lane's h column

    // fragment-plane bases: tile = q*16 + slice*8 + ctq
    u32 bb[6];
    #pragma unroll
    for (int q = 0; q < 6; ++q)
        bb[q] = (u32)(q * 16 + slice * 8 + wv) * 16384u + (u32)l * 8u;

    const u32 NL = *nlev_p;

    for (u32 L = 0; L < NL; ++L) {
        const u32 lcnt   = lvl_cnt[L];
        const u32 lst    = lvl_start[L];
        const u32 nchunk = (lcnt + ROWS - 1) / ROWS;

        for (u32 ck = sub; ck < nchunk; ck += 128) {
            if (tid < ROWS) {
                u32 i = ck * ROWS + (u32)tid;
                int valid = (i < lcnt);
                u16 e = valid ? wl[lst + i] : (u16)0;
                rval[tid] = (unsigned char)valid;
                int b_ = valid ? (e >> 8) : 0;
                int t_ = valid ? (e & 0xFF) : 0;
                brow[tid] = b_;
                trow[tid] = t_;
                nid[tid]  = node_ids[(size_t)b_ * CN + t_];
            }
            if (tid < ROWS * CK) {
                int lb = tid / 3, k = tid - lb * 3;
                u32 i = ck * ROWS + (u32)lb;
                int valid = (i < lcnt);
                u16 e = valid ? wl[lst + i] : (u16)0;
                int b_ = valid ? (e >> 8) : 0;
                int t_ = valid ? (e & 0xFF) : 0;
                int raw = children[((size_t)b_ * CN + t_) * CK + k];
                int v = (raw < t_) && valid;
                msk[lb][k] = v ? 1.0f : 0.0f;
                cix[lb][k] = v ? raw : 0;
            }
            __syncthreads();

            // stage x: 32 rows x 64 float4; pack hi|lo in-register
            for (int idx = tid; idx < ROWS * 64; idx += 512) {
                int row = idx >> 6, c4 = idx & 63;
                float4v v = *(const float4v*)(emb + (size_t)nid[row] * CE + c4 * 4);
                uint4v p;
                #pragma unroll
                for (int j = 0; j < 4; ++j) {
                    u16 hb = f2bfu(v[j]);
                    u16 lb = f2bfu(v[j] - bfu2f(hb));
                    p[j] = ((u32)hb << 16) | (u32)lb;
                }
                *(uint4v*)&Apk[row][c4 * 4] = p;
            }
            // stage h: straight copy of packed h_pk (sc1 agent-scope)
            for (int idx = tid; idx < ROWS * CK * 128; idx += 512) {
                int r  = idx >> 7;             // 0..95
                int ch = idx & 127;
                int row = r / 3, k = r - row * 3;
                u64 v = 0;
                if (msk[row][k] != 0.0f) {
                    const u64* src = (const u64*)(h_pk
                        + ((size_t)cix[row][k] * CB + brow[row]) * CH + 2 * ch);
                    v = __hip_atomic_load(src, __ATOMIC_RELAXED, __HIP_MEMORY_SCOPE_AGENT);
                }
                *(u64*)&Apk[row][CE + k * CH + 2 * ch] = v;
            }
            __syncthreads();

            // MFMA bf16x3: 32 k-iters, 6 gate planes, BOTH row-groups per
            // wave with one B fragment load
            float4v accH[2][6], accL[2][6];
            #pragma unroll
            for (int rg = 0; rg < 2; ++rg)
                #pragma unroll
                for (int q = 0; q < 6; ++q) {
                    accH[rg][q] = (float4v){0.f, 0.f, 0.f, 0.f};
                    accL[rg][q] = (float4v){0.f, 0.f, 0.f, 0.f};
                }
            #pragma unroll 2
            for (int ci = 0; ci < 32; ++ci) {
                short8v ahi[2], alo[2];
                #pragma unroll
                for (int rg = 0; rg < 2; ++rg) {
                    uint4v a0 = *(const uint4v*)&Apk[rg * 16 + lan15][ci * 32 + k8w];
                    uint4v a1 = *(const uint4v*)&Apk[rg * 16 + lan15][ci * 32 + k8w + 4];
                    #pragma unroll
                    for (int j = 0; j < 4; ++j) {
                        ahi[rg][j]     = (short)(a0[j] >> 16);
                        alo[rg][j]     = (short)(a0[j] & 0xffffu);
                        ahi[rg][4 + j] = (short)(a1[j] >> 16);
                        alo[rg][4 + j] = (short)(a1[j] & 0xffffu);
                    }
                }
                #pragma unroll
                for (int q = 0; q < 6; ++q) {
                    short8v bh = *(const short8v*)(Whi + bb[q] + ci * 512);
                    short8v bl = *(const short8v*)(Wlo + bb[q] + ci * 512);
                    #pragma unroll
                    for (int rg = 0; rg < 2; ++rg) {
                        accH[rg][q] = __builtin_amdgcn_mfma_f32_16x16x32_bf16(ahi[rg], bh, accH[rg][q], 0, 0, 0);
                        accL[rg][q] = __builtin_amdgcn_mfma_f32_16x16x32_bf16(ahi[rg], bl, accL[rg][q], 0, 0, 0);
                        accL[rg][q] = __builtin_amdgcn_mfma_f32_16x16x32_bf16(alo[rg], bh, accL[rg][q], 0, 0, 0);
                    }
                }
            }

            // fused cell phase, in-lane on D-layout (col=l&15, row=(l>>4)*4+r)
            #pragma unroll
            for (int rg = 0; rg < 2; ++rg)
            #pragma unroll
            for (int r = 0; r < 4; ++r) {
                const int row = rg * 16 + (l >> 4) * 4 + r;
                if (rval[row]) {
                    const int b = brow[row], t_ = trow[row];
                    const float m0 = msk[row][0], m1 = msk[row][1], m2 = msk[row][2];
                    float g[6];
                    #pragma unroll
                    for (int q = 0; q < 6; ++q) {
                        int gc = q * CH + hcol;
                        g[q] = accH[rg][q][r] + accL[rg][q][r]
                             + Wx_b[gc] + m0 * Uh_b[gc] + m1 * Uh_b[CG_ + gc]
                                        + m2 * Uh_b[2 * CG_ + gc];
                    }
                    float ig = 1.0f / (1.0f + expf(-g[0]));
                    float og = 1.0f / (1.0f + expf(-g[1]));
                    float ug = tanhf(g[2]);
                    float c = ig * ug;
                    if (m0 != 0.0f) c += (1.0f / (1.0f + expf(-g[3]))) *
                        __hip_atomic_load(&c_s[((size_t)cix[row][0] * CB + b) * CH + hcol],
                                          __ATOMIC_RELAXED, __HIP_MEMORY_SCOPE_AGENT);
                    if (m1 != 0.0f) c += (1.0f / (1.0f + expf(-g[4]))) *
                        __hip_atomic_load(&c_s[((size_t)cix[row][1] * CB + b) * CH + hcol],
                                          __ATOMIC_RELAXED, __HIP_MEMORY_SCOPE_AGENT);
                    if (m2 != 0.0f) c += (1.0f / (1.0f + expf(-g[5]))) *
                        __hip_atomic_load(&c_s[((size_t)cix[row][2] * CB + b) * CH + hcol],
                                          __ATOMIC_RELAXED, __HIP_MEMORY_SCOPE_AGENT);
                    float h = og * tanhf(c);
                    const size_t hx = ((size_t)t_ * CB + b) * CH + hcol;
                    u16 hb = f2bfu(h);
                    u32 hp = ((u32)hb << 16) | (u32)f2bfu(h - bfu2f(hb));
                    __hip_atomic_store(&h_pk[hx], hp, __ATOMIC_RELAXED, __HIP_MEMORY_SCOPE_AGENT);
                    __hip_atomic_store(&c_s[hx], c, __ATOMIC_RELAXED, __HIP_MEMORY_SCOPE_AGENT);
                    if (t_ == CN - 1) out[(size_t)b * CH + hcol] = h;
                }
            }
            __syncthreads();                   // Apk free before next stage
        }

        if (L == NL - 1) break;

        // ---- light grid barrier per level (r12/r14-r17 verified) ----
        __syncthreads();
        if (tid == 0)
            __hip_atomic_store(&flags[bid * 16], L + 1,
                               __ATOMIC_RELAXED, __HIP_MEMORY_SCOPE_AGENT);
        for (;;) {
            int ok = 1;
            if (tid < 256)
                ok = (__hip_atomic_load(&flags[tid * 16], __ATOMIC_RELAXED,
                                        __HIP_MEMORY_SCOPE_AGENT) >= L + 1);
            if (__syncthreads_and(ok)) break;
            __builtin_amdgcn_s_sleep(2);
        }
    }
}

// ---------------------------------------------------------------------------
// Fallback: per-step kernel with fragment-ordered B (r17-verified pathless
// backup, used only if the coop launch fails or ws is too small).
// ---------------------------------------------------------------------------
__global__ __launch_bounds__(768) void tree_step_mfma(
    const int* __restrict__ node_ids, const int* __restrict__ children,
    const float* __restrict__ emb,
    const u16* __restrict__ Whi, const u16* __restrict__ Wlo,
    const float* __restrict__ Wx_b, const float* __restrict__ Uh_b,
    u16* __restrict__ h_hi, u16* __restrict__ h_lo,
    float* __restrict__ c_s, float* __restrict__ out, const int t)
{
    const int tid = threadIdx.x;
    const int xcd  = blockIdx.x & 7;
    const int bidx = blockIdx.x >> 3;
    const int hi   = xcd * 2 + (bidx & 1);
    const int bi   = bidx >> 1;
    const int b0   = bi * 16;
    const int hh0  = hi * 16;

    __shared__ u16   Ahi[16][KTOT + 8];
    __shared__ u16   Alo[16][KTOT + 8];
    __shared__ float part[4][6][16][17];
    __shared__ int   nid[16];
    __shared__ float msk[16][3];
    __shared__ int   cix[16][3];

    const int wv    = tid >> 6;
    const int l     = tid & 63;
    const int np    = wv % 3;
    const int kq    = wv / 3;
    const int lan15 = l & 15;
    const int k8    = (l >> 4) * 8;

    if (tid < 16) nid[tid] = node_ids[(size_t)(b0 + tid) * CN + t];
    if (tid < 48) {
        int lb = tid / 3, k = tid - lb * 3;
        int raw = children[((size_t)(b0 + lb) * CN + t) * CK + k];
        int v = raw < t;
        msk[lb][k] = v ? 1.0f : 0.0f;
        cix[lb][k] = v ? raw : 0;
    }
    __syncthreads();

    for (int idx = tid; idx < 1024; idx += 768) {
        int lb = idx >> 6, c4 = idx & 63;
        float4v v = *(const float4v*)(emb + (size_t)nid[lb] * CE + c4 * 4);
        ushort4v h4, l4;
        #pragma unroll
        for (int j = 0; j < 4; ++j) {
            u16 hb = f2bfu(v[j]);
            h4[j] = hb;
            l4[j] = f2bfu(v[j] - bfu2f(hb));
        }
        *(ushort4v*)&Ahi[lb][c4 * 4] = h4;
        *(ushort4v*)&Alo[lb][c4 * 4] = l4;
    }
    for (int idx = tid; idx < 3072; idx += 768) {
        int r  = idx >> 6;
        int c  = idx & 63;
        int pl = c >> 5;
        int ch = c & 31;
        int lb = r / 3, k = r - lb * 3;
        uint4v val = (uint4v){0u, 0u, 0u, 0u};
        if (msk[lb][k] != 0.0f) {
            const u16* src = (pl ? h_lo : h_hi)
                + ((size_t)cix[lb][k] * CB + (b0 + lb)) * CH + ch * 8;
            val = *(const uint4v*)src;
        }
        u16* dst = (pl ? &Alo[lb][CE + k * CH + ch * 8]
                       : &Ahi[lb][CE + k * CH + ch * 8]);
        *(uint4v*)dst = val;
    }
    __syncthreads();

    {
        float4v acc[2][3];
        #pragma unroll
        for (int a = 0; a < 2; ++a)
            #pragma unroll
            for (int b2 = 0; b2 < 3; ++b2)
                acc[a][b2] = (float4v){0.f, 0.f, 0.f, 0.f};
        u32 fb0 = (u32)((np * 2 + 0) * 16 + hi) * 16384u + (u32)l * 8u;
        u32 fb1 = (u32)((np * 2 + 1) * 16 + hi) * 16384u + (u32)l * 8u;
        #pragma unroll
        for (int ci = 0; ci < 8; ++ci) {
            const int kb = (kq * 8 + ci) * 32 + k8;
            const u32 fo = (u32)(kq * 8 + ci) * 512u;
            short8v ahi = *(const short8v*)&Ahi[lan15][kb];
            short8v alo = *(const short8v*)&Alo[lan15][kb];
            short8v bh0 = *(const short8v*)(Whi + fb0 + fo);
            short8v bh1 = *(const short8v*)(Whi + fb1 + fo);
            short8v bl0 = *(const short8v*)(Wlo + fb0 + fo);
            short8v bl1 = *(const short8v*)(Wlo + fb1 + fo);
            acc[0][0] = __builtin_amdgcn_mfma_f32_16x16x32_bf16(ahi, bh0, acc[0][0], 0, 0, 0);
            acc[0][1] = __builtin_amdgcn_mfma_f32_16x16x32_bf16(ahi, bl0, acc[0][1], 0, 0, 0);
            acc[0][2] = __builtin_amdgcn_mfma_f32_16x16x32_bf16(alo, bh0, acc[0][2], 0, 0, 0);
            acc[1][0] = __builtin_amdgcn_mfma_f32_16x16x32_bf16(ahi, bh1, acc[1][0], 0, 0, 0);
            acc[1][1] = __builtin_amdgcn_mfma_f32_16x16x32_bf16(ahi, bl1, acc[1][1], 0, 0, 0);
            acc[1][2] = __builtin_amdgcn_mfma_f32_16x16x32_bf16(alo, bh1, acc[1][2], 0, 0, 0);
        }
        #pragma unroll
        for (int t2 = 0; t2 < 2; ++t2)
            #pragma unroll
            for (int r = 0; r < 4; ++r)
                part[kq][np * 2 + t2][(l >> 4) * 4 + r][lan15] =
                    acc[t2][0][r] + acc[t2][1][r] + acc[t2][2][r];
    }
    __syncthreads();

    if (tid < 256) {
        const int bb = tid >> 4, j2 = tid & 15;
        const int b = b0 + bb, hh = hh0 + j2;
        const float m0 = msk[bb][0], m1 = msk[bb][1], m2 = msk[bb][2];
        float g[6];
        #pragma unroll
        for (int q = 0; q < 6; ++q) {
            int gc = q * CH + hh;
            g[q] = part[0][q][bb][j2] + part[1][q][bb][j2]
                 + part[2][q][bb][j2] + part[3][q][bb][j2]
                 + Wx_b[gc] + m0 * Uh_b[gc] + m1 * Uh_b[CG_ + gc]
                            + m2 * Uh_b[2 * CG_ + gc];
        }
        float ig = 1.0f / (1.0f + expf(-g[0]));
        float og = 1.0f / (1.0f + expf(-g[1]));
        float ug = tanhf(g[2]);
        float c = ig * ug;
        if (m0 != 0.0f) c += (1.0f / (1.0f + expf(-g[3]))) * c_s[((size_t)cix[bb][0] * CB + b) * CH + hh];
        if (m1 != 0.0f) c += (1.0f / (1.0f + expf(-g[4]))) * c_s[((size_t)cix[bb][1] * CB + b) * CH + hh];
        if (m2 != 0.0f) c += (1.0f / (1.0f + expf(-g[5]))) * c_s[((size_t)cix[bb][2] * CB + b) * CH + hh];
        float h = og * tanhf(c);
        const size_t hx = ((size_t)t * CB + b) * CH + hh;
        u16 hb = f2bfu(h);
        h_hi[hx] = hb;
        h_lo[hx] = f2bfu(h - bfu2f(hb));
        c_s[hx] = c;
        if (t == CN - 1) out[(size_t)b * CH + hh] = h;
    }
}

__global__ void ws_report(float* out, int n, float val) {
    int i = blockIdx.x * blockDim.x + threadIdx.x;
    if (i < n) out[i] = val;
}

// ---------------------------------------------------------------------------
extern "C" void kernel_launch(void* const* d_in, const int* in_sizes, int n_in,
                              void* d_out, int out_size, void* d_ws, size_t ws_size,
                              hipStream_t stream) {
    float* outp = (float*)d_out;

    const int expect_sizes[7] = {65536, 196608, 8192000, 393216, 1536, 1179648, 4608};
    int bad = -1;
    if (n_in != 7) bad = 7;
    else for (int i = 0; i < 7; ++i) if (in_sizes[i] != expect_sizes[i]) { bad = i; break; }
    if (bad >= 0) {
        ws_report<<<(out_size + 255) / 256, 256, 0, stream>>>(outp, out_size, 1000.0f + bad);
        return;
    }

    const int*   node_ids = (const int*)d_in[0];
    const int*   children = (const int*)d_in[1];
    const float* emb      = (const float*)d_in[2];
    const float* Wx_w     = (const float*)d_in[3];
    const float* Wx_b     = (const float*)d_in[4];
    const float* Uh_w     = (const float*)d_in[5];
    const float* Uh_b     = (const float*)d_in[6];

    const size_t w_plane  = (size_t)CG_ * KTOT * 2;       //  3,145,728 B
    const size_t st_elems = (size_t)CN * CB * CH;         // 16,777,216
    const size_t flags_sz = 256 * 16 * sizeof(u32);       // 16 KB
    const size_t wl_sz    = (size_t)CB * CN * sizeof(u16);// 128 KB
    const size_t lvl_sz   = 256 * sizeof(u32);

    size_t off = 0;
    const size_t o_whi = off; off += w_plane;
    const size_t o_wlo = off; off += w_plane;
    const size_t o_hpk = off; off += st_elems * 4;
    const size_t o_cs  = off; off += st_elems * 4;
    const size_t o_flg = off; off += flags_sz;
    const size_t o_wl  = off; off += wl_sz;
    const size_t o_ls  = off; off += lvl_sz;
    const size_t o_lc  = off; off += lvl_sz;
    const size_t o_nl  = off; off += 64;
    const size_t need_lvl  = off;
    const size_t need_step = 2 * w_plane + st_elems * 2 * 2 + st_elems * 4;

    if (ws_size >= need_lvl) {
        char* w = (char*)d_ws;
        u16*   Whi = (u16*)(w + o_whi);
        u16*   Wlo = (u16*)(w + o_wlo);
        u32*   hpk = (u32*)(w + o_hpk);
        float* csb = (float*)(w + o_cs);
        u32*   flg = (u32*)(w + o_flg);
        u16*   wlp = (u16*)(w + o_wl);
        u32*   lsp = (u32*)(w + o_ls);
        u32*   lcp = (u32*)(w + o_lc);
        u32*   nlp = (u32*)(w + o_nl);

        prep_w<<<dim3(CG_), dim3(256), 0, stream>>>(Wx_w, Uh_w, Whi, Wlo);
        build_sched<<<dim3(1), dim3(256), 0, stream>>>(children, wlp, lsp, lcp, nlp);
        hipMemsetAsync(flg, 0, flags_sz, stream);

        void* args[] = { (void*)&node_ids, (void*)&children, (void*)&emb,
                         (void*)&Whi, (void*)&Wlo, (void*)&Wx_b, (void*)&Uh_b,
                         (void*)&hpk, (void*)&csb, (void*)&flg,
                         (void*)&wlp, (void*)&lsp, (void*)&lcp, (void*)&nlp,
                         (void*)&outp };
        hipError_t e = hipLaunchCooperativeKernel((const void*)tree_scan_lvl,
                                                  dim3(256), dim3(512), args, 0, stream);
        if (e == hipSuccess) return;
    }
    if (ws_size >= need_step) {
        char* w = (char*)d_ws;
        u16*   Whi = (u16*)w;
        u16*   Wlo = (u16*)(w + w_plane);
        u16*   hhi = (u16*)(w + 2 * w_plane);
        u16*   hlo = (u16*)(w + 2 * w_plane + st_elems * 2);
        float* csb = (float*)(w + 2 * w_plane + 2 * st_elems * 2);

        prep_w<<<dim3(CG_), dim3(256), 0, stream>>>(Wx_w, Uh_w, Whi, Wlo);
        for (int t = 0; t < CN; ++t)
            tree_step_mfma<<<dim3(256), dim3(768), 0, stream>>>(
                node_ids, children, emb, Whi, Wlo, Wx_b, Uh_b,
                hhi, hlo, csb, outp, t);
    } else {
        ws_report<<<(out_size + 255) / 256, 256, 0, stream>>>(
            outp, out_size, (float)(ws_size >> 20));
    }
}

// Round 19
// 2032.475 us; speedup vs baseline: 2.2017x; 1.0360x over previous
//
#include <hip/hip_runtime.h>
#include <hip/hip_bf16.h>

#define CB 256      // batch
#define CN 256      // nodes
#define CK 3        // children per node
#define CE 256      // embedding dim
#define CH 256      // hidden dim
#define CG_ 1536    // gates = 6*CH
#define KTOT 1024   // E + K*H
#define ROWS 32     // rows per chunk
#define ASTRW 1028  // Apk row stride in u32 words

typedef __attribute__((ext_vector_type(8))) short short8v;          // 8 bf16
typedef __attribute__((ext_vector_type(4))) float float4v;          // MFMA C/D
typedef __attribute__((ext_vector_type(4))) unsigned int uint4v;
typedef __attribute__((ext_vector_type(4))) unsigned short ushort4v;
typedef unsigned int u32;
typedef unsigned long long u64;
typedef unsigned short u16;

__device__ __forceinline__ u16 f2bfu(float v) {
    __hip_bfloat16 h = __float2bfloat16(v);
    return __builtin_bit_cast(u16, h);
}
__device__ __forceinline__ float bfu2f(u16 u) {
    __hip_bfloat16 h = __builtin_bit_cast(__hip_bfloat16, u);
    return __bfloat162float(h);
}

// ---------------------------------------------------------------------------
// Prep (verified r17/r18): split W = [Wx_w ; Uh_w] into bf16 hi/lo planes in
// MFMA-FRAGMENT order [tile(16 gate cols)][ci][lane][8] — wave B-load = 1 KB
// contiguous.
// ---------------------------------------------------------------------------
__global__ __launch_bounds__(256) void prep_w(
    const float* __restrict__ Wx_w, const float* __restrict__ Uh_w,
    u16* __restrict__ Whi, u16* __restrict__ Wlo)
{
    const int g    = blockIdx.x;           // gate col 0..1535
    const int tile = g >> 4;
    const int gl   = g & 15;
    for (int k = threadIdx.x; k < KTOT; k += 256) {
        float w = (k < CE) ? Wx_w[(size_t)k * CG_ + g]
                           : Uh_w[(size_t)(k - CE) * CG_ + g];
        u16 hi = f2bfu(w);
        u16 lo = f2bfu(w - bfu2f(hi));
        int ci = k >> 5, kr = k & 31, lq = kr >> 3, j = kr & 7;
        size_t idx = ((size_t)(tile * 32 + ci) * 64 + lq * 16 + gl) * 8 + j;
        Whi[idx] = hi;
        Wlo[idx] = lo;
    }
}

// ---------------------------------------------------------------------------
// Level schedule build (verified r14-r18, incl. the 0xFFFF-collision fix).
// ---------------------------------------------------------------------------
__global__ __launch_bounds__(256) void build_sched(
    const int* __restrict__ children,
    u16* __restrict__ wl,             // [65536] (b<<8)|t
    u32* __restrict__ lvl_start,      // [256]
    u32* __restrict__ lvl_cnt,        // [256]
    u32* __restrict__ nlev)           // [1]
{
    __shared__ unsigned char lvl[CB][CN];   // 64 KB
    __shared__ u32 cnt[CN];
    __shared__ u32 pos[CN];
    const int b = threadIdx.x;

    for (int t = 0; t < CN; ++t) {
        int lv = 0;
        #pragma unroll
        for (int k = 0; k < CK; ++k) {
            int raw = children[((size_t)b * CN + t) * CK + k];
            if (raw < t) { int cl = (int)lvl[b][raw] + 1; if (cl > lv) lv = cl; }
        }
        lvl[b][t] = (unsigned char)lv;
    }
    cnt[b] = 0;
    __syncthreads();
    for (int t = 0; t < CN; ++t) atomicAdd(&cnt[lvl[b][t]], 1u);
    __syncthreads();
    if (b == 0) {
        u32 acc = 0, nl = 0;
        for (int L = 0; L < CN; ++L) {
            pos[L] = acc;
            if (cnt[L]) nl = (u32)L + 1;
            acc += cnt[L];
        }
        *nlev = nl;
    }
    __syncthreads();
    lvl_cnt[b]   = cnt[b];
    lvl_start[b] = pos[b];
    __syncthreads();
    for (int t = 0; t < CN; ++t) {
        int L = lvl[b][t];
        u32 p = atomicAdd(&pos[L], 1u);
        wl[p] = (u16)((b << 8) | t);
    }
}

// ---------------------------------------------------------------------------
// r19 scan = r18 structure with PLAIN (cacheable) state LOADS.
// Safety argument: h_pk/c_s entries are written exactly ONCE per launch
// (task recomputed every launch), and only read after the producing level's
// barrier; caches are invalidated at kernel launch -> a plain load can never
// observe stale data (it misses L2 and fetches the fresh MALL copy, then
// CACHES it -> shared children become L2/L1 hits). Only STORES (cross-XCD
// publish) and barrier flags need sc1. Empirical support: r10/r11 per-step
// path used plain state loads across launches and validated.
// Gather also vectorized 8B -> 16B. Everything else identical to r18.
// ---------------------------------------------------------------------------
__global__ __launch_bounds__(512, 2) void tree_scan_lvl(
    const int* __restrict__ node_ids,          // [B][N]
    const int* __restrict__ children,          // [B][N][K]
    const float* __restrict__ emb,             // [V][E]
    const u16* __restrict__ Whi,               // fragment-ordered
    const u16* __restrict__ Wlo,               // fragment-ordered
    const float* __restrict__ Wx_b,            // [G]
    const float* __restrict__ Uh_b,            // [K][G]
    u32* __restrict__ h_pk,                    // [N][B][H] u32 (hi16|lo16)
    float* __restrict__ c_s,                   // [N][B][H] f32
    u32* __restrict__ flags,                   // [256*16], zeroed per call
    const u16* __restrict__ wl,                // [65536]
    const u32* __restrict__ lvl_start,         // [256]
    const u32* __restrict__ lvl_cnt,           // [256]
    const u32* __restrict__ nlev_p,            // [1]
    float* __restrict__ out)                   // [B][H] f32
{
    const int tid = threadIdx.x;
    const int bid = blockIdx.x;
    const int xcd   = bid & 7;
    const int slice = xcd >> 2;                          // 0..1 (4 XCDs each)
    const int sub   = ((bid >> 3) << 2) | (bid & 3);     // 0..127
    const int hh0   = slice * 128;

    __shared__ u32   Apk[ROWS][ASTRW];         // 131,584 B (hi|lo packed)
    __shared__ int   nid[ROWS], brow[ROWS], trow[ROWS];
    __shared__ unsigned char rval[ROWS];
    __shared__ float msk[ROWS][3];
    __shared__ int   cix[ROWS][3];

    const int wv    = tid >> 6;                // 0..7 = col-tile (ctq)
    const int l     = tid & 63;
    const int lan15 = l & 15;
    const int k8w   = (l >> 4) * 8;            // k-offset inside A row
    const int hcol  = hh0 + wv * 16 + lan15;   // this lane's h column

    // fragment-plane bases: tile = q*16 + slice*8 + ctq
    u32 bb[6];
    #pragma unroll
    for (int q = 0; q < 6; ++q)
        bb[q] = (u32)(q * 16 + slice * 8 + wv) * 16384u + (u32)l * 8u;

    const u32 NL = *nlev_p;

    for (u32 L = 0; L < NL; ++L) {
        const u32 lcnt   = lvl_cnt[L];
        const u32 lst    = lvl_start[L];
        const u32 nchunk = (lcnt + ROWS - 1) / ROWS;

        for (u32 ck = sub; ck < nchunk; ck += 128) {
            if (tid < ROWS) {
                u32 i = ck * ROWS + (u32)tid;
                int valid = (i < lcnt);
                u16 e = valid ? wl[lst + i] : (u16)0;
                rval[tid] = (unsigned char)valid;
                int b_ = valid ? (e >> 8) : 0;
                int t_ = valid ? (e & 0xFF) : 0;
                brow[tid] = b_;
                trow[tid] = t_;
                nid[tid]  = node_ids[(size_t)b_ * CN + t_];
            }
            if (tid < ROWS * CK) {
                int lb = tid / 3, k = tid - lb * 3;
                u32 i = ck * ROWS + (u32)lb;
                int valid = (i < lcnt);
                u16 e = valid ? wl[lst + i] : (u16)0;
                int b_ = valid ? (e >> 8) : 0;
                int t_ = valid ? (e & 0xFF) : 0;
                int raw = children[((size_t)b_ * CN + t_) * CK + k];
                int v = (raw < t_) && valid;
                msk[lb][k] = v ? 1.0f : 0.0f;
                cix[lb][k] = v ? raw : 0;
            }
            __syncthreads();

            // stage x: 32 rows x 64 float4; pack hi|lo in-register
            for (int idx = tid; idx < ROWS * 64; idx += 512) {
                int row = idx >> 6, c4 = idx & 63;
                float4v v = *(const float4v*)(emb + (size_t)nid[row] * CE + c4 * 4);
                uint4v p;
                #pragma unroll
                for (int j = 0; j < 4; ++j) {
                    u16 hb = f2bfu(v[j]);
                    u16 lb = f2bfu(v[j] - bfu2f(hb));
                    p[j] = ((u32)hb << 16) | (u32)lb;
                }
                *(uint4v*)&Apk[row][c4 * 4] = p;
            }
            // stage h: 96 (row,k) pairs x 64 16B chunks — PLAIN cacheable
            // loads of the packed h_pk format (write-once state, see header)
            for (int idx = tid; idx < ROWS * CK * 64; idx += 512) {
                int r  = idx >> 6;             // 0..95
                int ch = idx & 63;             // 16B chunk
                int row = r / 3, k = r - row * 3;
                uint4v v = (uint4v){0u, 0u, 0u, 0u};
                if (msk[row][k] != 0.0f) {
                    const uint4v* src = (const uint4v*)(h_pk
                        + ((size_t)cix[row][k] * CB + brow[row]) * CH + 4 * ch);
                    v = *src;
                }
                *(uint4v*)&Apk[row][CE + k * CH + 4 * ch] = v;
            }
            __syncthreads();

            // MFMA bf16x3: 32 k-iters, 6 gate planes, BOTH row-groups per
            // wave with one B fragment load
            float4v accH[2][6], accL[2][6];
            #pragma unroll
            for (int rg = 0; rg < 2; ++rg)
                #pragma unroll
                for (int q = 0; q < 6; ++q) {
                    accH[rg][q] = (float4v){0.f, 0.f, 0.f, 0.f};
                    accL[rg][q] = (float4v){0.f, 0.f, 0.f, 0.f};
                }
            #pragma unroll 2
            for (int ci = 0; ci < 32; ++ci) {
                short8v ahi[2], alo[2];
                #pragma unroll
                for (int rg = 0; rg < 2; ++rg) {
                    uint4v a0 = *(const uint4v*)&Apk[rg * 16 + lan15][ci * 32 + k8w];
                    uint4v a1 = *(const uint4v*)&Apk[rg * 16 + lan15][ci * 32 + k8w + 4];
                    #pragma unroll
                    for (int j = 0; j < 4; ++j) {
                        ahi[rg][j]     = (short)(a0[j] >> 16);
                        alo[rg][j]     = (short)(a0[j] & 0xffffu);
                        ahi[rg][4 + j] = (short)(a1[j] >> 16);
                        alo[rg][4 + j] = (short)(a1[j] & 0xffffu);
                    }
                }
                #pragma unroll
                for (int q = 0; q < 6; ++q) {
                    short8v bh = *(const short8v*)(Whi + bb[q] + ci * 512);
                    short8v bl = *(const short8v*)(Wlo + bb[q] + ci * 512);
                    #pragma unroll
                    for (int rg = 0; rg < 2; ++rg) {
                        accH[rg][q] = __builtin_amdgcn_mfma_f32_16x16x32_bf16(ahi[rg], bh, accH[rg][q], 0, 0, 0);
                        accL[rg][q] = __builtin_amdgcn_mfma_f32_16x16x32_bf16(ahi[rg], bl, accL[rg][q], 0, 0, 0);
                        accL[rg][q] = __builtin_amdgcn_mfma_f32_16x16x32_bf16(alo[rg], bh, accL[rg][q], 0, 0, 0);
                    }
                }
            }

            // fused cell phase, in-lane on D-layout (col=l&15, row=(l>>4)*4+r)
            #pragma unroll
            for (int rg = 0; rg < 2; ++rg)
            #pragma unroll
            for (int r = 0; r < 4; ++r) {
                const int row = rg * 16 + (l >> 4) * 4 + r;
                if (rval[row]) {
                    const int b = brow[row], t_ = trow[row];
                    const float m0 = msk[row][0], m1 = msk[row][1], m2 = msk[row][2];
                    float g[6];
                    #pragma unroll
                    for (int q = 0; q < 6; ++q) {
                        int gc = q * CH + hcol;
                        g[q] = accH[rg][q][r] + accL[rg][q][r]
                             + Wx_b[gc] + m0 * Uh_b[gc] + m1 * Uh_b[CG_ + gc]
                                        + m2 * Uh_b[2 * CG_ + gc];
                    }
                    float ig = 1.0f / (1.0f + expf(-g[0]));
                    float og = 1.0f / (1.0f + expf(-g[1]));
                    float ug = tanhf(g[2]);
                    float c = ig * ug;
                    if (m0 != 0.0f) c += (1.0f / (1.0f + expf(-g[3]))) *
                        c_s[((size_t)cix[row][0] * CB + b) * CH + hcol];
                    if (m1 != 0.0f) c += (1.0f / (1.0f + expf(-g[4]))) *
                        c_s[((size_t)cix[row][1] * CB + b) * CH + hcol];
                    if (m2 != 0.0f) c += (1.0f / (1.0f + expf(-g[5]))) *
                        c_s[((size_t)cix[row][2] * CB + b) * CH + hcol];
                    float h = og * tanhf(c);
                    const size_t hx = ((size_t)t_ * CB + b) * CH + hcol;
                    u16 hb = f2bfu(h);
                    u32 hp = ((u32)hb << 16) | (u32)f2bfu(h - bfu2f(hb));
                    __hip_atomic_store(&h_pk[hx], hp, __ATOMIC_RELAXED, __HIP_MEMORY_SCOPE_AGENT);
                    __hip_atomic_store(&c_s[hx], c, __ATOMIC_RELAXED, __HIP_MEMORY_SCOPE_AGENT);
                    if (t_ == CN - 1) out[(size_t)b * CH + hcol] = h;
                }
            }
            __syncthreads();                   // Apk free before next stage
        }

        if (L == NL - 1) break;

        // ---- light grid barrier per level (r12/r14-r18 verified) ----
        __syncthreads();
        if (tid == 0)
            __hip_atomic_store(&flags[bid * 16], L + 1,
                               __ATOMIC_RELAXED, __HIP_MEMORY_SCOPE_AGENT);
        for (;;) {
            int ok = 1;
            if (tid < 256)
                ok = (__hip_atomic_load(&flags[tid * 16], __ATOMIC_RELAXED,
                                        __HIP_MEMORY_SCOPE_AGENT) >= L + 1);
            if (__syncthreads_and(ok)) break;
            __builtin_amdgcn_s_sleep(2);
        }
    }
}

// ---------------------------------------------------------------------------
// Fallback: per-step kernel with fragment-ordered B (r17/r18-verified backup).
// ---------------------------------------------------------------------------
__global__ __launch_bounds__(768) void tree_step_mfma(
    const int* __restrict__ node_ids, const int* __restrict__ children,
    const float* __restrict__ emb,
    const u16* __restrict__ Whi, const u16* __restrict__ Wlo,
    const float* __restrict__ Wx_b, const float* __restrict__ Uh_b,
    u16* __restrict__ h_hi, u16* __restrict__ h_lo,
    float* __restrict__ c_s, float* __restrict__ out, const int t)
{
    const int tid = threadIdx.x;
    const int xcd  = blockIdx.x & 7;
    const int bidx = blockIdx.x >> 3;
    const int hi   = xcd * 2 + (bidx & 1);
    const int bi   = bidx >> 1;
    const int b0   = bi * 16;
    const int hh0  = hi * 16;

    __shared__ u16   Ahi[16][KTOT + 8];
    __shared__ u16   Alo[16][KTOT + 8];
    __shared__ float part[4][6][16][17];
    __shared__ int   nid[16];
    __shared__ float msk[16][3];
    __shared__ int   cix[16][3];

    const int wv    = tid >> 6;
    const int l     = tid & 63;
    const int np    = wv % 3;
    const int kq    = wv / 3;
    const int lan15 = l & 15;
    const int k8    = (l >> 4) * 8;

    if (tid < 16) nid[tid] = node_ids[(size_t)(b0 + tid) * CN + t];
    if (tid < 48) {
        int lb = tid / 3, k = tid - lb * 3;
        int raw = children[((size_t)(b0 + lb) * CN + t) * CK + k];
        int v = raw < t;
        msk[lb][k] = v ? 1.0f : 0.0f;
        cix[lb][k] = v ? raw : 0;
    }
    __syncthreads();

    for (int idx = tid; idx < 1024; idx += 768) {
        int lb = idx >> 6, c4 = idx & 63;
        float4v v = *(const float4v*)(emb + (size_t)nid[lb] * CE + c4 * 4);
        ushort4v h4, l4;
        #pragma unroll
        for (int j = 0; j < 4; ++j) {
            u16 hb = f2bfu(v[j]);
            h4[j] = hb;
            l4[j] = f2bfu(v[j] - bfu2f(hb));
        }
        *(ushort4v*)&Ahi[lb][c4 * 4] = h4;
        *(ushort4v*)&Alo[lb][c4 * 4] = l4;
    }
    for (int idx = tid; idx < 3072; idx += 768) {
        int r  = idx >> 6;
        int c  = idx & 63;
        int pl = c >> 5;
        int ch = c & 31;
        int lb = r / 3, k = r - lb * 3;
        uint4v val = (uint4v){0u, 0u, 0u, 0u};
        if (msk[lb][k] != 0.0f) {
            const u16* src = (pl ? h_lo : h_hi)
                + ((size_t)cix[lb][k] * CB + (b0 + lb)) * CH + ch * 8;
            val = *(const uint4v*)src;
        }
        u16* dst = (pl ? &Alo[lb][CE + k * CH + ch * 8]
                       : &Ahi[lb][CE + k * CH + ch * 8]);
        *(uint4v*)dst = val;
    }
    __syncthreads();

    {
        float4v acc[2][3];
        #pragma unroll
        for (int a = 0; a < 2; ++a)
            #pragma unroll
            for (int b2 = 0; b2 < 3; ++b2)
                acc[a][b2] = (float4v){0.f, 0.f, 0.f, 0.f};
        u32 fb0 = (u32)((np * 2 + 0) * 16 + hi) * 16384u + (u32)l * 8u;
        u32 fb1 = (u32)((np * 2 + 1) * 16 + hi) * 16384u + (u32)l * 8u;
        #pragma unroll
        for (int ci = 0; ci < 8; ++ci) {
            const int kb = (kq * 8 + ci) * 32 + k8;
            const u32 fo = (u32)(kq * 8 + ci) * 512u;
            short8v ahi = *(const short8v*)&Ahi[lan15][kb];
            short8v alo = *(const short8v*)&Alo[lan15][kb];
            short8v bh0 = *(const short8v*)(Whi + fb0 + fo);
            short8v bh1 = *(const short8v*)(Whi + fb1 + fo);
            short8v bl0 = *(const short8v*)(Wlo + fb0 + fo);
            short8v bl1 = *(const short8v*)(Wlo + fb1 + fo);
            acc[0][0] = __builtin_amdgcn_mfma_f32_16x16x32_bf16(ahi, bh0, acc[0][0], 0, 0, 0);
            acc[0][1] = __builtin_amdgcn_mfma_f32_16x16x32_bf16(ahi, bl0, acc[0][1], 0, 0, 0);
            acc[0][2] = __builtin_amdgcn_mfma_f32_16x16x32_bf16(alo, bh0, acc[0][2], 0, 0, 0);
            acc[1][0] = __builtin_amdgcn_mfma_f32_16x16x32_bf16(ahi, bh1, acc[1][0], 0, 0, 0);
            acc[1][1] = __builtin_amdgcn_mfma_f32_16x16x32_bf16(ahi, bl1, acc[1][1], 0, 0, 0);
            acc[1][2] = __builtin_amdgcn_mfma_f32_16x16x32_bf16(alo, bh1, acc[1][2], 0, 0, 0);
        }
        #pragma unroll
        for (int t2 = 0; t2 < 2; ++t2)
            #pragma unroll
            for (int r = 0; r < 4; ++r)
                part[kq][np * 2 + t2][(l >> 4) * 4 + r][lan15] =
                    acc[t2][0][r] + acc[t2][1][r] + acc[t2][2][r];
    }
    __syncthreads();

    if (tid < 256) {
        const int bb = tid >> 4, j2 = tid & 15;
        const int b = b0 + bb, hh = hh0 + j2;
        const float m0 = msk[bb][0], m1 = msk[bb][1], m2 = msk[bb][2];
        float g[6];
        #pragma unroll
        for (int q = 0; q < 6; ++q) {
            int gc = q * CH + hh;
            g[q] = part[0][q][bb][j2] + part[1][q][bb][j2]
                 + part[2][q][bb][j2] + part[3][q][bb][j2]
                 + Wx_b[gc] + m0 * Uh_b[gc] + m1 * Uh_b[CG_ + gc]
                            + m2 * Uh_b[2 * CG_ + gc];
        }
        float ig = 1.0f / (1.0f + expf(-g[0]));
        float og = 1.0f / (1.0f + expf(-g[1]));
        float ug = tanhf(g[2]);
        float c = ig * ug;
        if (m0 != 0.0f) c += (1.0f / (1.0f + expf(-g[3]))) * c_s[((size_t)cix[bb][0] * CB + b) * CH + hh];
        if (m1 != 0.0f) c += (1.0f / (1.0f + expf(-g[4]))) * c_s[((size_t)cix[bb][1] * CB + b) * CH + hh];
        if (m2 != 0.0f) c += (1.0f / (1.0f + expf(-g[5]))) * c_s[((size_t)cix[bb][2] * CB + b) * CH + hh];
        float h = og * tanhf(c);
        const size_t hx = ((size_t)t * CB + b) * CH + hh;
        u16 hb = f2bfu(h);
        h_hi[hx] = hb;
        h_lo[hx] = f2bfu(h - bfu2f(hb));
        c_s[hx] = c;
        if (t == CN - 1) out[(size_t)b * CH + hh] = h;
    }
}

__global__ void ws_report(float* out, int n, float val) {
    int i = blockIdx.x * blockDim.x + threadIdx.x;
    if (i < n) out[i] = val;
}

// ---------------------------------------------------------------------------
extern "C" void kernel_launch(void* const* d_in, const int* in_sizes, int n_in,
                              void* d_out, int out_size, void* d_ws, size_t ws_size,
                              hipStream_t stream) {
    float* outp = (float*)d_out;

    const int expect_sizes[7] = {65536, 196608, 8192000, 393216, 1536, 1179648, 4608};
    int bad = -1;
    if (n_in != 7) bad = 7;
    else for (int i = 0; i < 7; ++i) if (in_sizes[i] != expect_sizes[i]) { bad = i; break; }
    if (bad >= 0) {
        ws_report<<<(out_size + 255) / 256, 256, 0, stream>>>(outp, out_size, 1000.0f + bad);
        return;
    }

    const int*   node_ids = (const int*)d_in[0];
    const int*   children = (const int*)d_in[1];
    const float* emb      = (const float*)d_in[2];
    const float* Wx_w     = (const float*)d_in[3];
    const float* Wx_b     = (const float*)d_in[4];
    const float* Uh_w     = (const float*)d_in[5];
    const float* Uh_b     = (const float*)d_in[6];

    const size_t w_plane  = (size_t)CG_ * KTOT * 2;       //  3,145,728 B
    const size_t st_elems = (size_t)CN * CB * CH;         // 16,777,216
    const size_t flags_sz = 256 * 16 * sizeof(u32);       // 16 KB
    const size_t wl_sz    = (size_t)CB * CN * sizeof(u16);// 128 KB
    const size_t lvl_sz   = 256 * sizeof(u32);

    size_t off = 0;
    const size_t o_whi = off; off += w_plane;
    const size_t o_wlo = off; off += w_plane;
    const size_t o_hpk = off; off += st_elems * 4;
    const size_t o_cs  = off; off += st_elems * 4;
    const size_t o_flg = off; off += flags_sz;
    const size_t o_wl  = off; off += wl_sz;
    const size_t o_ls  = off; off += lvl_sz;
    const size_t o_lc  = off; off += lvl_sz;
    const size_t o_nl  = off; off += 64;
    const size_t need_lvl  = off;
    const size_t need_step = 2 * w_plane + st_elems * 2 * 2 + st_elems * 4;

    if (ws_size >= need_lvl) {
        char* w = (char*)d_ws;
        u16*   Whi = (u16*)(w + o_whi);
        u16*   Wlo = (u16*)(w + o_wlo);
        u32*   hpk = (u32*)(w + o_hpk);
        float* csb = (float*)(w + o_cs);
        u32*   flg = (u32*)(w + o_flg);
        u16*   wlp = (u16*)(w + o_wl);
        u32*   lsp = (u32*)(w + o_ls);
        u32*   lcp = (u32*)(w + o_lc);
        u32*   nlp = (u32*)(w + o_nl);

        prep_w<<<dim3(CG_), dim3(256), 0, stream>>>(Wx_w, Uh_w, Whi, Wlo);
        build_sched<<<dim3(1), dim3(256), 0, stream>>>(children, wlp, lsp, lcp, nlp);
        hipMemsetAsync(flg, 0, flags_sz, stream);

        void* args[] = { (void*)&node_ids, (void*)&children, (void*)&emb,
                         (void*)&Whi, (void*)&Wlo, (void*)&Wx_b, (void*)&Uh_b,
                         (void*)&hpk, (void*)&csb, (void*)&flg,
                         (void*)&wlp, (void*)&lsp, (void*)&lcp, (void*)&nlp,
                         (void*)&outp };
        hipError_t e = hipLaunchCooperativeKernel((const void*)tree_scan_lvl,
                                                  dim3(256), dim3(512), args, 0, stream);
        if (e == hipSuccess) return;
    }
    if (ws_size >= need_step) {
        char* w = (char*)d_ws;
        u16*   Whi = (u16*)w;
        u16*   Wlo = (u16*)(w + w_plane);
        u16*   hhi = (u16*)(w + 2 * w_plane);
        u16*   hlo = (u16*)(w + 2 * w_plane + st_elems * 2);
        float* csb = (float*)(w + 2 * w_plane + 2 * st_elems * 2);

        prep_w<<<dim3(CG_), dim3(256), 0, stream>>>(Wx_w, Uh_w, Whi, Wlo);
        for (int t = 0; t < CN; ++t)
            tree_step_mfma<<<dim3(256), dim3(768), 0, stream>>>(
                node_ids, children, emb, Whi, Wlo, Wx_b, Uh_b,
                hhi, hlo, csb, outp, t);
    } else {
        ws_report<<<(out_size + 255) / 256, 256, 0, stream>>>(
            outp, out_size, (float)(ws_size >> 20));
    }
}